// Round 1
// baseline (258.669 us; speedup 1.0000x reference)
//
#include <hip/hip_runtime.h>
#include <hip/hip_bf16.h>

// Problem constants
#define BATCH 128
#define NIN   1024
#define NFULL 4096
#define R1    48
#define R2    16
#define FCDIM 512
#define NOUT  10

// Workspace layout (float offsets). Total = 7,815,168 floats (~29.8 MiB).
#define WS_C1  0
#define WS_D1  4096
#define WS_C2  8192
#define WS_D2  12288
#define WS_Q1  16384
#define WS_GP1 (WS_Q1 + R1*NFULL)        // 212992
#define WS_Q2  (WS_GP1 + R1*NFULL)       // 409600
#define WS_GP2 (WS_Q2 + R2*NFULL)        // 475136
#define WS_P1  (WS_GP2 + R2*NFULL)       // 540672
#define WS_P2  (WS_P1 + BATCH*NIN)       // 671744
#define WS_H2  (WS_P2 + BATCH*NFULL)     // 1196032
#define WS_VP  (WS_H2 + BATCH*FCDIM)     // 1261568  (4 x 128 x 512)
#define WS_PT1 (WS_VP + 4*BATCH*FCDIM)   // 1523712  (1024 x 4096)
#define WS_P2M (WS_PT1 + NIN*NFULL)      // 5718016  (512 x 4096)
#define WS_END (WS_P2M + FCDIM*NFULL)    // 7815168

// ---------------------------------------------------------------------------
// c = [1, cumprod(src)] for 4 arrays. Block b handles one array.
// 256 threads x 16 elements, Hillis-Steele scan of per-thread products.
__global__ void cumprod_kernel(const float* __restrict__ sA1, const float* __restrict__ sB1,
                               const float* __restrict__ sA2, const float* __restrict__ sB2,
                               float* __restrict__ ws) {
    const float* src = (blockIdx.x == 0) ? sA1 : (blockIdx.x == 1) ? sB1
                      : (blockIdx.x == 2) ? sA2 : sB2;
    float* dst = ws + (size_t)blockIdx.x * 4096;
    __shared__ float tot[256];
    int t = threadIdx.x;
    float loc[16];
    float prod = 1.f;
#pragma unroll
    for (int k = 0; k < 16; ++k) {
        int idx = t * 16 + k;
        float e = (idx == 0) ? 1.f : src[idx - 1];
        prod *= e;
        loc[k] = prod;
    }
    tot[t] = prod;
    __syncthreads();
    for (int off = 1; off < 256; off <<= 1) {
        float v = (t >= off) ? tot[t - off] : 1.f;
        __syncthreads();
        tot[t] *= v;
        __syncthreads();
    }
    float excl = (t == 0) ? 1.f : tot[t - 1];
#pragma unroll
    for (int k = 0; k < 16; ++k) dst[t * 16 + k] = excl * loc[k];
}

// ---------------------------------------------------------------------------
// Elementwise prep: q1=H1/d1, gp1=G1/c1, q2=H2/d2, gp2=G2/c2, p1=x*d1[:1024]
__global__ void prep_kernel(const float* __restrict__ x, const float* __restrict__ G1,
                            const float* __restrict__ H1, const float* __restrict__ G2,
                            const float* __restrict__ H2, float* __restrict__ ws) {
    const float* c1 = ws + WS_C1;
    const float* d1 = ws + WS_D1;
    const float* c2 = ws + WS_C2;
    const float* d2 = ws + WS_D2;
    int idx = blockIdx.x * 256 + threadIdx.x;
    const int E1 = R1 * NFULL;            // 196608
    const int E2 = R2 * NFULL;            // 65536
    if (idx < E1) {
        int k = idx & (NFULL - 1);
        ws[WS_Q1 + idx] = H1[idx] / d1[k];
    } else if (idx < 2 * E1) {
        int j = idx - E1;
        int k = j & (NFULL - 1);
        ws[WS_GP1 + j] = G1[j] / c1[k];
    } else if (idx < 2 * E1 + E2) {
        int j = idx - 2 * E1;
        int k = j & (NFULL - 1);
        ws[WS_Q2 + j] = H2[j] / d2[k];
    } else if (idx < 2 * E1 + 2 * E2) {
        int j = idx - 2 * E1 - E2;
        int k = j & (NFULL - 1);
        ws[WS_GP2 + j] = G2[j] / c2[k];
    } else if (idx < 2 * E1 + 2 * E2 + BATCH * NIN) {
        int j = idx - 2 * E1 - 2 * E2;
        int m = j & (NIN - 1);
        ws[WS_P1 + j] = x[j] * d1[m];
    }
}

// ---------------------------------------------------------------------------
// Rank-K outer-product GEMM: C[m][n] = sum_r A[r*ld + m0+m] * B[r*ld + n0+n]
// Tile 64x64, 256 threads, each 4x4. Kr <= 48 loaded fully into LDS.
__global__ void gemm_rank_kernel(const float* __restrict__ A, const float* __restrict__ B,
                                 float* __restrict__ C, int Mo, int No, int Kr, int ld) {
    __shared__ float As[48 * 64];
    __shared__ float Bs[48 * 64];
    int tid = threadIdx.x;
    int tx = tid & 15, ty = tid >> 4;
    int n0 = blockIdx.x * 64;
    int m0 = blockIdx.y * 64;
    int tot = Kr * 64;
    for (int lin = tid; lin < tot; lin += 256) {
        int r = lin >> 6, i = lin & 63;
        As[lin] = A[r * ld + m0 + i];
        Bs[lin] = B[r * ld + n0 + i];
    }
    __syncthreads();
    float acc[4][4] = {};
    for (int r = 0; r < Kr; ++r) {
        float a4[4], b4[4];
#pragma unroll
        for (int i = 0; i < 4; ++i) a4[i] = As[r * 64 + ty * 4 + i];
#pragma unroll
        for (int j = 0; j < 4; ++j) b4[j] = Bs[r * 64 + tx * 4 + j];
#pragma unroll
        for (int i = 0; i < 4; ++i)
#pragma unroll
            for (int j = 0; j < 4; ++j) acc[i][j] += a4[i] * b4[j];
    }
#pragma unroll
    for (int i = 0; i < 4; ++i) {
        int m = m0 + ty * 4 + i;
#pragma unroll
        for (int j = 0; j < 4; ++j) {
            C[(size_t)m * No + n0 + tx * 4 + j] = acc[i][j];
        }
    }
}

// ---------------------------------------------------------------------------
// In-place diagonal prefix sum: P[r][c] += P[r-1][c-1]; one thread/diagonal,
// 8-wide batched loads to hide latency.
__global__ void diag_scan_kernel(float* __restrict__ P, int R, int C) {
    int t = blockIdx.x * blockDim.x + threadIdx.x;
    int nd = R + C - 1;
    if (t >= nd) return;
    int r, c;
    if (t < C) { r = 0; c = t; } else { r = t - C + 1; c = 0; }
    int len = min(R - r, C - c);
    float run = 0.f;
    float* p = P + (size_t)r * C + c;
    const int step = C + 1;
    int s = 0;
    for (; s + 8 <= len; s += 8) {
        float v[8];
#pragma unroll
        for (int u = 0; u < 8; ++u) v[u] = p[(size_t)u * step];
#pragma unroll
        for (int u = 0; u < 8; ++u) { run += v[u]; v[u] = run; }
#pragma unroll
        for (int u = 0; u < 8; ++u) p[(size_t)u * step] = v[u];
        p += (size_t)8 * step;
    }
    for (; s < len; ++s) { run += *p; *p = run; p += step; }
}

// ---------------------------------------------------------------------------
// Layer-1 GEMM2: p2[b][n] = relu(c1[n]*(p1 @ Mt1)[b][n] + b1[n]) * d2[n]
// A = p1 (128x1024), B = Mt1 (1024x4096 row-major [k][n]). Tile 32x64, K=32.
__global__ void gemm2_l1_kernel(const float* __restrict__ p1, const float* __restrict__ Mt1,
                                const float* __restrict__ c1, const float* __restrict__ b1,
                                const float* __restrict__ d2, float* __restrict__ p2) {
    __shared__ float As[32][33];
    __shared__ float Bs[32][65];
    int tid = threadIdx.x;
    int tx = tid & 15, ty = tid >> 4;
    int n0 = blockIdx.x * 64;
    int m0 = blockIdx.y * 32;
    float acc[2][4] = {};
    for (int k0 = 0; k0 < NIN; k0 += 32) {
#pragma unroll
        for (int l = 0; l < 4; ++l) {
            int lin = tid + l * 256;
            int bi = lin >> 5, ki = lin & 31;
            As[bi][ki] = p1[(size_t)(m0 + bi) * NIN + k0 + ki];
        }
#pragma unroll
        for (int l = 0; l < 8; ++l) {
            int lin = tid + l * 256;
            int ki = lin >> 6, ni = lin & 63;
            Bs[ki][ni] = Mt1[(size_t)(k0 + ki) * NFULL + n0 + ni];
        }
        __syncthreads();
#pragma unroll
        for (int kk = 0; kk < 32; ++kk) {
            float a0 = As[ty * 2 + 0][kk];
            float a1 = As[ty * 2 + 1][kk];
            float b4[4];
#pragma unroll
            for (int j = 0; j < 4; ++j) b4[j] = Bs[kk][tx * 4 + j];
#pragma unroll
            for (int j = 0; j < 4; ++j) {
                acc[0][j] += a0 * b4[j];
                acc[1][j] += a1 * b4[j];
            }
        }
        __syncthreads();
    }
#pragma unroll
    for (int i = 0; i < 2; ++i) {
        int b = m0 + ty * 2 + i;
#pragma unroll
        for (int j = 0; j < 4; ++j) {
            int n = n0 + tx * 4 + j;
            float y = c1[n] * acc[i][j] + b1[n];
            y = y > 0.f ? y : 0.f;
            p2[(size_t)b * NFULL + n] = y * d2[n];
        }
    }
}

// ---------------------------------------------------------------------------
// Layer-2 GEMM2 (split-K=4): vpart[z][b][n] = sum_{k in chunk} p2[b][k]*M2[n][k]
// A = p2 (128x4096), B^T = M2 (512x4096 row-major [n][k]). Tile 32x64, K=32.
__global__ void gemm2_l2_kernel(const float* __restrict__ p2, const float* __restrict__ M2,
                                float* __restrict__ vpart) {
    __shared__ float As[32][33];
    __shared__ float Bs[32][65];
    int tid = threadIdx.x;
    int tx = tid & 15, ty = tid >> 4;
    int n0 = blockIdx.x * 64;
    int m0 = blockIdx.y * 32;
    int kbase = blockIdx.z * 1024;
    float acc[2][4] = {};
    for (int k0 = kbase; k0 < kbase + 1024; k0 += 32) {
#pragma unroll
        for (int l = 0; l < 4; ++l) {
            int lin = tid + l * 256;
            int bi = lin >> 5, ki = lin & 31;
            As[bi][ki] = p2[(size_t)(m0 + bi) * NFULL + k0 + ki];
        }
#pragma unroll
        for (int l = 0; l < 8; ++l) {
            int lin = tid + l * 256;
            int ni = lin >> 5, ki = lin & 31;
            Bs[ki][ni] = M2[(size_t)(n0 + ni) * NFULL + k0 + ki];
        }
        __syncthreads();
#pragma unroll
        for (int kk = 0; kk < 32; ++kk) {
            float a0 = As[ty * 2 + 0][kk];
            float a1 = As[ty * 2 + 1][kk];
            float b4[4];
#pragma unroll
            for (int j = 0; j < 4; ++j) b4[j] = Bs[kk][tx * 4 + j];
#pragma unroll
            for (int j = 0; j < 4; ++j) {
                acc[0][j] += a0 * b4[j];
                acc[1][j] += a1 * b4[j];
            }
        }
        __syncthreads();
    }
#pragma unroll
    for (int i = 0; i < 2; ++i) {
        int b = m0 + ty * 2 + i;
#pragma unroll
        for (int j = 0; j < 4; ++j) {
            int n = n0 + tx * 4 + j;
            vpart[((size_t)blockIdx.z * BATCH + b) * FCDIM + n] = acc[i][j];
        }
    }
}

// ---------------------------------------------------------------------------
// h2[b][i] = relu(c2[i]*(sum of 4 split-K partials) + b2[i])
__global__ void h2_kernel(const float* __restrict__ vpart, const float* __restrict__ c2,
                          const float* __restrict__ b2, float* __restrict__ h2) {
    int idx = blockIdx.x * 256 + threadIdx.x;   // 65536 total
    int i = idx & (FCDIM - 1);
    float s = vpart[idx] + vpart[BATCH * FCDIM + idx] + vpart[2 * BATCH * FCDIM + idx] +
              vpart[3 * BATCH * FCDIM + idx];
    float y = c2[i] * s + b2[i];
    h2[idx] = y > 0.f ? y : 0.f;
}

// ---------------------------------------------------------------------------
// logits[b][o] = sum_i h2[b][i] * Wl[o][i] + bl[o]; one 64-lane wave per (b,o)
__global__ void logits_kernel(const float* __restrict__ h2, const float* __restrict__ Wl,
                              const float* __restrict__ bl, float* __restrict__ out) {
    int bb = blockIdx.x / NOUT;
    int o = blockIdx.x % NOUT;
    int lane = threadIdx.x;
    float s = 0.f;
#pragma unroll
    for (int i = lane; i < FCDIM; i += 64) s += h2[(size_t)bb * FCDIM + i] * Wl[(size_t)o * FCDIM + i];
#pragma unroll
    for (int off = 32; off > 0; off >>= 1) s += __shfl_down(s, off);
    if (lane == 0) out[(size_t)bb * NOUT + o] = s + bl[o];
}

// ---------------------------------------------------------------------------
extern "C" void kernel_launch(void* const* d_in, const int* in_sizes, int n_in,
                              void* d_out, int out_size, void* d_ws, size_t ws_size,
                              hipStream_t stream) {
    const float* x   = (const float*)d_in[0];
    const float* G1  = (const float*)d_in[1];
    const float* H1  = (const float*)d_in[2];
    const float* sA1 = (const float*)d_in[3];
    const float* sB1 = (const float*)d_in[4];
    const float* b1  = (const float*)d_in[5];
    const float* G2  = (const float*)d_in[6];
    const float* H2  = (const float*)d_in[7];
    const float* sA2 = (const float*)d_in[8];
    const float* sB2 = (const float*)d_in[9];
    const float* b2  = (const float*)d_in[10];
    const float* Wl  = (const float*)d_in[11];
    const float* bl  = (const float*)d_in[12];
    float* out = (float*)d_out;
    float* ws = (float*)d_ws;
    (void)in_sizes; (void)n_in; (void)out_size; (void)ws_size;

    // 1. cumprods: c1, d1, c2, d2
    cumprod_kernel<<<4, 256, 0, stream>>>(sA1, sB1, sA2, sB2, ws);

    // 2. prep: q1, gp1, q2, gp2, p1  (655360 elements)
    prep_kernel<<<2560, 256, 0, stream>>>(x, G1, H1, G2, H2, ws);

    // 3. Rank-K GEMMs: Pt1[m][i] = sum_r q1[r,m]*gp1[r,i]  (1024 x 4096)
    gemm_rank_kernel<<<dim3(64, 16), 256, 0, stream>>>(ws + WS_Q1, ws + WS_GP1, ws + WS_PT1,
                                                       NIN, NFULL, R1, NFULL);
    //    P2[i][m] = sum_r gp2[r,i]*q2[r,m]  (512 x 4096)
    gemm_rank_kernel<<<dim3(64, 8), 256, 0, stream>>>(ws + WS_GP2, ws + WS_Q2, ws + WS_P2M,
                                                      FCDIM, NFULL, R2, NFULL);

    // 4. Diagonal scans -> Mt1, M2 (in place)
    diag_scan_kernel<<<80, 64, 0, stream>>>(ws + WS_PT1, NIN, NFULL);   // 5119 diagonals
    diag_scan_kernel<<<72, 64, 0, stream>>>(ws + WS_P2M, FCDIM, NFULL); // 4607 diagonals

    // 5. GEMM2 layer 1 (epilogue: relu + scale) -> p2
    gemm2_l1_kernel<<<dim3(64, 4), 256, 0, stream>>>(ws + WS_P1, ws + WS_PT1, ws + WS_C1,
                                                     b1, ws + WS_D2, ws + WS_P2);

    // 6. GEMM2 layer 2 (split-K=4) -> vpart
    gemm2_l2_kernel<<<dim3(8, 4, 4), 256, 0, stream>>>(ws + WS_P2, ws + WS_P2M, ws + WS_VP);

    // 7. reduce + epilogue -> h2
    h2_kernel<<<256, 256, 0, stream>>>(ws + WS_VP, ws + WS_C2, b2, ws + WS_H2);

    // 8. logits
    logits_kernel<<<BATCH * NOUT, 64, 0, stream>>>(ws + WS_H2, Wl, bl, out);
}

// Round 2
// 165.453 us; speedup vs baseline: 1.5634x; 1.5634x over previous
//
#include <hip/hip_runtime.h>
#include <hip/hip_bf16.h>

// Problem constants
#define BATCH 128
#define NIN   1024
#define NFULL 4096
#define R1    48
#define R2    16
#define FCDIM 512
#define NOUT  10

// Workspace layout (float offsets).
#define WS_C1  0
#define WS_D1  4096
#define WS_C2  8192
#define WS_D2  12288
#define WS_Q1  16384
#define WS_GP1 (WS_Q1 + R1*NFULL)        // 212992
#define WS_Q2  (WS_GP1 + R1*NFULL)       // 409600
#define WS_GP2 (WS_Q2 + R2*NFULL)        // 475136
#define WS_P1  (WS_GP2 + R2*NFULL)       // 540672
#define WS_P2  (WS_P1 + BATCH*NIN)       // 671744
#define WS_H2  (WS_P2 + BATCH*NFULL)     // 1196032
#define WS_VP  (WS_H2 + BATCH*FCDIM)     // 1261568  (4 x 128 x 512)
#define WS_PT1 (WS_VP + 4*BATCH*FCDIM)   // 1523712  (1024 x 4096)
#define WS_P2M (WS_PT1 + NIN*NFULL)      // 5718016  (512 x 4096)
#define WS_CT1 (WS_P2M + FCDIM*NFULL)    // 7815168  (8 x 5120 chunk totals, scan 1)
#define WS_CT2 (WS_CT1 + 8*5120)         // 7856128  (8 x 4608 chunk totals, scan 2)
#define WS_END (WS_CT2 + 8*4608)         // 7892992 floats (~30.1 MiB)

// Scan geometry
#define ND1 (NIN + NFULL - 1)    // 5119 diagonals, matrix 1 (1024 x 4096)
#define ND2 (FCDIM + NFULL - 1)  // 4607 diagonals, matrix 2 (512 x 4096)
#define NCH 8
#define CH1 (NIN / NCH)          // 128 rows per chunk
#define CH2 (FCDIM / NCH)        // 64 rows per chunk

// ---------------------------------------------------------------------------
// c = [1, cumprod(src)] for 4 arrays. Block b handles one array.
__global__ void cumprod_kernel(const float* __restrict__ sA1, const float* __restrict__ sB1,
                               const float* __restrict__ sA2, const float* __restrict__ sB2,
                               float* __restrict__ ws) {
    const float* src = (blockIdx.x == 0) ? sA1 : (blockIdx.x == 1) ? sB1
                      : (blockIdx.x == 2) ? sA2 : sB2;
    float* dst = ws + (size_t)blockIdx.x * 4096;
    __shared__ float tot[256];
    int t = threadIdx.x;
    float loc[16];
    float prod = 1.f;
#pragma unroll
    for (int k = 0; k < 16; ++k) {
        int idx = t * 16 + k;
        float e = (idx == 0) ? 1.f : src[idx - 1];
        prod *= e;
        loc[k] = prod;
    }
    tot[t] = prod;
    __syncthreads();
    for (int off = 1; off < 256; off <<= 1) {
        float v = (t >= off) ? tot[t - off] : 1.f;
        __syncthreads();
        tot[t] *= v;
        __syncthreads();
    }
    float excl = (t == 0) ? 1.f : tot[t - 1];
#pragma unroll
    for (int k = 0; k < 16; ++k) dst[t * 16 + k] = excl * loc[k];
}

// ---------------------------------------------------------------------------
// Elementwise prep: q1=H1/d1, gp1=G1/c1, q2=H2/d2, gp2=G2/c2, p1=x*d1[:1024]
__global__ void prep_kernel(const float* __restrict__ x, const float* __restrict__ G1,
                            const float* __restrict__ H1, const float* __restrict__ G2,
                            const float* __restrict__ H2, float* __restrict__ ws) {
    const float* c1 = ws + WS_C1;
    const float* d1 = ws + WS_D1;
    const float* c2 = ws + WS_C2;
    const float* d2 = ws + WS_D2;
    int idx = blockIdx.x * 256 + threadIdx.x;
    const int E1 = R1 * NFULL;            // 196608
    const int E2 = R2 * NFULL;            // 65536
    if (idx < E1) {
        int k = idx & (NFULL - 1);
        ws[WS_Q1 + idx] = H1[idx] / d1[k];
    } else if (idx < 2 * E1) {
        int j = idx - E1;
        int k = j & (NFULL - 1);
        ws[WS_GP1 + j] = G1[j] / c1[k];
    } else if (idx < 2 * E1 + E2) {
        int j = idx - 2 * E1;
        int k = j & (NFULL - 1);
        ws[WS_Q2 + j] = H2[j] / d2[k];
    } else if (idx < 2 * E1 + 2 * E2) {
        int j = idx - 2 * E1 - E2;
        int k = j & (NFULL - 1);
        ws[WS_GP2 + j] = G2[j] / c2[k];
    } else if (idx < 2 * E1 + 2 * E2 + BATCH * NIN) {
        int j = idx - 2 * E1 - 2 * E2;
        int m = j & (NIN - 1);
        ws[WS_P1 + j] = x[j] * d1[m];
    }
}

// ---------------------------------------------------------------------------
// Rank-K outer-product GEMM: C[m][n] = sum_r A[r*ld + m0+m] * B[r*ld + n0+n]
__global__ void gemm_rank_kernel(const float* __restrict__ A, const float* __restrict__ B,
                                 float* __restrict__ C, int Mo, int No, int Kr, int ld) {
    __shared__ float As[48 * 64];
    __shared__ float Bs[48 * 64];
    int tid = threadIdx.x;
    int tx = tid & 15, ty = tid >> 4;
    int n0 = blockIdx.x * 64;
    int m0 = blockIdx.y * 64;
    int tot = Kr * 64;
    for (int lin = tid; lin < tot; lin += 256) {
        int r = lin >> 6, i = lin & 63;
        As[lin] = A[r * ld + m0 + i];
        Bs[lin] = B[r * ld + n0 + i];
    }
    __syncthreads();
    float acc[4][4] = {};
    for (int r = 0; r < Kr; ++r) {
        float a4[4], b4[4];
#pragma unroll
        for (int i = 0; i < 4; ++i) a4[i] = As[r * 64 + ty * 4 + i];
#pragma unroll
        for (int j = 0; j < 4; ++j) b4[j] = Bs[r * 64 + tx * 4 + j];
#pragma unroll
        for (int i = 0; i < 4; ++i)
#pragma unroll
            for (int j = 0; j < 4; ++j) acc[i][j] += a4[i] * b4[j];
    }
#pragma unroll
    for (int i = 0; i < 4; ++i) {
        int m = m0 + ty * 4 + i;
#pragma unroll
        for (int j = 0; j < 4; ++j) {
            C[(size_t)m * No + n0 + tx * 4 + j] = acc[i][j];
        }
    }
}

// ---------------------------------------------------------------------------
// Chunked diagonal prefix sum, phase 1 (both matrices in one launch).
// Thread t owns diagonal offset d = t-(R-1); within row-chunk z it computes
// the chunk-local prefix in place (coalesced: at fixed row m, consecutive t
// touch consecutive addresses) and stores the chunk total.
__global__ void diag_scan_p1(float* __restrict__ ws) {
    const int which = blockIdx.z;
    float* P        = ws + (which == 0 ? WS_PT1 : WS_P2M);
    float* ctot     = ws + (which == 0 ? WS_CT1 : WS_CT2);
    const int R     = which == 0 ? NIN : FCDIM;
    const int CH    = which == 0 ? CH1 : CH2;
    const int nd    = R + NFULL - 1;
    const int ctld  = which == 0 ? 5120 : 4608;
    int t = blockIdx.x * 256 + threadIdx.x;
    if (t >= nd) return;
    int doff = t - (R - 1);
    int z = blockIdx.y;
    int m0 = z * CH;
    int mlo = max(m0, -doff);
    int mhi = min(m0 + CH, min(NFULL - doff, R));
    float run = 0.f;
    if (mlo < mhi) {
        float* p = P + (size_t)mlo * NFULL + (mlo + doff);
        const size_t step = NFULL + 1;
        int len = mhi - mlo;
        int s = 0;
        for (; s + 8 <= len; s += 8) {
            float v[8];
#pragma unroll
            for (int u = 0; u < 8; ++u) v[u] = p[u * step];
#pragma unroll
            for (int u = 0; u < 8; ++u) { run += v[u]; v[u] = run; }
#pragma unroll
            for (int u = 0; u < 8; ++u) p[u * step] = v[u];
            p += 8 * step;
        }
        for (; s < len; ++s) { float v = *p; run += v; *p = run; p += step; }
    }
    ctot[(size_t)z * ctld + t] = run;
}

// Phase 2: chunk z (1..NCH-1) adds the exclusive prefix of earlier chunk
// totals to every element of its diagonal segment.
__global__ void diag_scan_p2(float* __restrict__ ws) {
    const int which = blockIdx.z;
    float* P        = ws + (which == 0 ? WS_PT1 : WS_P2M);
    const float* ctot = ws + (which == 0 ? WS_CT1 : WS_CT2);
    const int R     = which == 0 ? NIN : FCDIM;
    const int CH    = which == 0 ? CH1 : CH2;
    const int nd    = R + NFULL - 1;
    const int ctld  = which == 0 ? 5120 : 4608;
    int t = blockIdx.x * 256 + threadIdx.x;
    if (t >= nd) return;
    int z = blockIdx.y + 1;
    float off = 0.f;
    for (int zz = 0; zz < z; ++zz) off += ctot[(size_t)zz * ctld + t];
    if (off == 0.f) return;
    int doff = t - (R - 1);
    int m0 = z * CH;
    int mlo = max(m0, -doff);
    int mhi = min(m0 + CH, min(NFULL - doff, R));
    if (mlo >= mhi) return;
    float* p = P + (size_t)mlo * NFULL + (mlo + doff);
    const size_t step = NFULL + 1;
    int len = mhi - mlo;
    int s = 0;
    for (; s + 8 <= len; s += 8) {
        float v[8];
#pragma unroll
        for (int u = 0; u < 8; ++u) v[u] = p[u * step];
#pragma unroll
        for (int u = 0; u < 8; ++u) v[u] += off;
#pragma unroll
        for (int u = 0; u < 8; ++u) p[u * step] = v[u];
        p += 8 * step;
    }
    for (; s < len; ++s) { *p += off; p += step; }
}

// ---------------------------------------------------------------------------
// Layer-1 GEMM2: p2[b][n] = relu(c1[n]*(p1 @ Mt1)[b][n] + b1[n]) * d2[n]
__global__ void gemm2_l1_kernel(const float* __restrict__ p1, const float* __restrict__ Mt1,
                                const float* __restrict__ c1, const float* __restrict__ b1,
                                const float* __restrict__ d2, float* __restrict__ p2) {
    __shared__ float As[32][33];
    __shared__ float Bs[32][65];
    int tid = threadIdx.x;
    int tx = tid & 15, ty = tid >> 4;
    int n0 = blockIdx.x * 64;
    int m0 = blockIdx.y * 32;
    float acc[2][4] = {};
    for (int k0 = 0; k0 < NIN; k0 += 32) {
#pragma unroll
        for (int l = 0; l < 4; ++l) {
            int lin = tid + l * 256;
            int bi = lin >> 5, ki = lin & 31;
            As[bi][ki] = p1[(size_t)(m0 + bi) * NIN + k0 + ki];
        }
#pragma unroll
        for (int l = 0; l < 8; ++l) {
            int lin = tid + l * 256;
            int ki = lin >> 6, ni = lin & 63;
            Bs[ki][ni] = Mt1[(size_t)(k0 + ki) * NFULL + n0 + ni];
        }
        __syncthreads();
#pragma unroll
        for (int kk = 0; kk < 32; ++kk) {
            float a0 = As[ty * 2 + 0][kk];
            float a1 = As[ty * 2 + 1][kk];
            float b4[4];
#pragma unroll
            for (int j = 0; j < 4; ++j) b4[j] = Bs[kk][tx * 4 + j];
#pragma unroll
            for (int j = 0; j < 4; ++j) {
                acc[0][j] += a0 * b4[j];
                acc[1][j] += a1 * b4[j];
            }
        }
        __syncthreads();
    }
#pragma unroll
    for (int i = 0; i < 2; ++i) {
        int b = m0 + ty * 2 + i;
#pragma unroll
        for (int j = 0; j < 4; ++j) {
            int n = n0 + tx * 4 + j;
            float y = c1[n] * acc[i][j] + b1[n];
            y = y > 0.f ? y : 0.f;
            p2[(size_t)b * NFULL + n] = y * d2[n];
        }
    }
}

// ---------------------------------------------------------------------------
// Layer-2 GEMM2 (split-K=4): vpart[z][b][n] = sum_{k in chunk} p2[b][k]*M2[n][k]
__global__ void gemm2_l2_kernel(const float* __restrict__ p2, const float* __restrict__ M2,
                                float* __restrict__ vpart) {
    __shared__ float As[32][33];
    __shared__ float Bs[32][65];
    int tid = threadIdx.x;
    int tx = tid & 15, ty = tid >> 4;
    int n0 = blockIdx.x * 64;
    int m0 = blockIdx.y * 32;
    int kbase = blockIdx.z * 1024;
    float acc[2][4] = {};
    for (int k0 = kbase; k0 < kbase + 1024; k0 += 32) {
#pragma unroll
        for (int l = 0; l < 4; ++l) {
            int lin = tid + l * 256;
            int bi = lin >> 5, ki = lin & 31;
            As[bi][ki] = p2[(size_t)(m0 + bi) * NFULL + k0 + ki];
        }
#pragma unroll
        for (int l = 0; l < 8; ++l) {
            int lin = tid + l * 256;
            int ni = lin >> 5, ki = lin & 31;
            Bs[ki][ni] = M2[(size_t)(n0 + ni) * NFULL + k0 + ki];
        }
        __syncthreads();
#pragma unroll
        for (int kk = 0; kk < 32; ++kk) {
            float a0 = As[ty * 2 + 0][kk];
            float a1 = As[ty * 2 + 1][kk];
            float b4[4];
#pragma unroll
            for (int j = 0; j < 4; ++j) b4[j] = Bs[kk][tx * 4 + j];
#pragma unroll
            for (int j = 0; j < 4; ++j) {
                acc[0][j] += a0 * b4[j];
                acc[1][j] += a1 * b4[j];
            }
        }
        __syncthreads();
    }
#pragma unroll
    for (int i = 0; i < 2; ++i) {
        int b = m0 + ty * 2 + i;
#pragma unroll
        for (int j = 0; j < 4; ++j) {
            int n = n0 + tx * 4 + j;
            vpart[((size_t)blockIdx.z * BATCH + b) * FCDIM + n] = acc[i][j];
        }
    }
}

// ---------------------------------------------------------------------------
// h2[b][i] = relu(c2[i]*(sum of 4 split-K partials) + b2[i])
__global__ void h2_kernel(const float* __restrict__ vpart, const float* __restrict__ c2,
                          const float* __restrict__ b2, float* __restrict__ h2) {
    int idx = blockIdx.x * 256 + threadIdx.x;   // 65536 total
    int i = idx & (FCDIM - 1);
    float s = vpart[idx] + vpart[BATCH * FCDIM + idx] + vpart[2 * BATCH * FCDIM + idx] +
              vpart[3 * BATCH * FCDIM + idx];
    float y = c2[i] * s + b2[i];
    h2[idx] = y > 0.f ? y : 0.f;
}

// ---------------------------------------------------------------------------
// logits[b][o] = sum_i h2[b][i] * Wl[o][i] + bl[o]; one 64-lane wave per (b,o)
__global__ void logits_kernel(const float* __restrict__ h2, const float* __restrict__ Wl,
                              const float* __restrict__ bl, float* __restrict__ out) {
    int bb = blockIdx.x / NOUT;
    int o = blockIdx.x % NOUT;
    int lane = threadIdx.x;
    float s = 0.f;
#pragma unroll
    for (int i = lane; i < FCDIM; i += 64) s += h2[(size_t)bb * FCDIM + i] * Wl[(size_t)o * FCDIM + i];
#pragma unroll
    for (int off = 32; off > 0; off >>= 1) s += __shfl_down(s, off);
    if (lane == 0) out[(size_t)bb * NOUT + o] = s + bl[o];
}

// ---------------------------------------------------------------------------
extern "C" void kernel_launch(void* const* d_in, const int* in_sizes, int n_in,
                              void* d_out, int out_size, void* d_ws, size_t ws_size,
                              hipStream_t stream) {
    const float* x   = (const float*)d_in[0];
    const float* G1  = (const float*)d_in[1];
    const float* H1  = (const float*)d_in[2];
    const float* sA1 = (const float*)d_in[3];
    const float* sB1 = (const float*)d_in[4];
    const float* b1  = (const float*)d_in[5];
    const float* G2  = (const float*)d_in[6];
    const float* H2  = (const float*)d_in[7];
    const float* sA2 = (const float*)d_in[8];
    const float* sB2 = (const float*)d_in[9];
    const float* b2  = (const float*)d_in[10];
    const float* Wl  = (const float*)d_in[11];
    const float* bl  = (const float*)d_in[12];
    float* out = (float*)d_out;
    float* ws = (float*)d_ws;
    (void)in_sizes; (void)n_in; (void)out_size; (void)ws_size;

    // 1. cumprods: c1, d1, c2, d2
    cumprod_kernel<<<4, 256, 0, stream>>>(sA1, sB1, sA2, sB2, ws);

    // 2. prep: q1, gp1, q2, gp2, p1  (655360 elements)
    prep_kernel<<<2560, 256, 0, stream>>>(x, G1, H1, G2, H2, ws);

    // 3. Rank-K GEMMs: Pt1[m][i] = sum_r q1[r,m]*gp1[r,i]  (1024 x 4096)
    gemm_rank_kernel<<<dim3(64, 16), 256, 0, stream>>>(ws + WS_Q1, ws + WS_GP1, ws + WS_PT1,
                                                       NIN, NFULL, R1, NFULL);
    //    P2[i][m] = sum_r gp2[r,i]*q2[r,m]  (512 x 4096)
    gemm_rank_kernel<<<dim3(64, 8), 256, 0, stream>>>(ws + WS_GP2, ws + WS_Q2, ws + WS_P2M,
                                                      FCDIM, NFULL, R2, NFULL);

    // 4. Diagonal scans -> Mt1, M2 (in place), chunked 2-phase, both fused
    diag_scan_p1<<<dim3(20, NCH, 2), 256, 0, stream>>>(ws);
    diag_scan_p2<<<dim3(20, NCH - 1, 2), 256, 0, stream>>>(ws);

    // 5. GEMM2 layer 1 (epilogue: relu + scale) -> p2
    gemm2_l1_kernel<<<dim3(64, 4), 256, 0, stream>>>(ws + WS_P1, ws + WS_PT1, ws + WS_C1,
                                                     b1, ws + WS_D2, ws + WS_P2);

    // 6. GEMM2 layer 2 (split-K=4) -> vpart
    gemm2_l2_kernel<<<dim3(8, 4, 4), 256, 0, stream>>>(ws + WS_P2, ws + WS_P2M, ws + WS_VP);

    // 7. reduce + epilogue -> h2
    h2_kernel<<<256, 256, 0, stream>>>(ws + WS_VP, ws + WS_C2, b2, ws + WS_H2);

    // 8. logits
    logits_kernel<<<BATCH * NOUT, 64, 0, stream>>>(ws + WS_H2, Wl, bl, out);
}

// Round 3
// 103.023 us; speedup vs baseline: 2.5108x; 1.6060x over previous
//
#include <hip/hip_runtime.h>
#include <hip/hip_bf16.h>

// Problem constants
#define BATCH 128
#define NIN   1024
#define NFULL 4096
#define R1    48
#define R2    16
#define FCDIM 512
#define NOUT  10

// Workspace layout (float offsets). Total 7,630,848 floats (~29.1 MiB).
#define WS_C1  0
#define WS_D1  4096
#define WS_C2  8192
#define WS_D2  12288
#define WS_Q1  16384
#define WS_GP1 (WS_Q1 + R1*NFULL)        // 212992
#define WS_Q2  (WS_GP1 + R1*NFULL)       // 409600
#define WS_GP2 (WS_Q2 + R2*NFULL)        // 475136
#define WS_P1  (WS_GP2 + R2*NFULL)       // 540672
#define WS_P2  (WS_P1 + BATCH*NIN)       // 671744
#define WS_H2  (WS_P2 + BATCH*NFULL)     // 1196032
#define WS_PT1 (WS_H2 + BATCH*FCDIM)     // 1261568  (1024 x 4096)
#define WS_P2M (WS_PT1 + NIN*NFULL)      // 5455872  (512 x 4096)
#define WS_CT1 (WS_P2M + FCDIM*NFULL)    // 7553024  (8 x 5120 chunk totals, scan 1)
#define WS_CT2 (WS_CT1 + 8*5120)         // 7593984  (8 x 4608 chunk totals, scan 2)
#define WS_END (WS_CT2 + 8*4608)         // 7630848
// Aliased (dead-region) scratch:
//   L1 partial slice 0 = WS_P2 region (in-place epilogue)
//   L1 partial slice 1 = WS_Q1 region (524288 floats, dead after rank GEMMs)
//   L2 partials (32 x 128 x 512 = 2M floats) = WS_PT1 region (dead after gemm2_l1)

// Scan geometry
#define NCH 8
#define CH1 (NIN / NCH)          // 128 rows per chunk
#define CH2 (FCDIM / NCH)        // 64 rows per chunk

// ---------------------------------------------------------------------------
// c = [1, cumprod(src)] for 4 arrays. Block b handles one array.
__global__ void cumprod_kernel(const float* __restrict__ sA1, const float* __restrict__ sB1,
                               const float* __restrict__ sA2, const float* __restrict__ sB2,
                               float* __restrict__ ws) {
    const float* src = (blockIdx.x == 0) ? sA1 : (blockIdx.x == 1) ? sB1
                      : (blockIdx.x == 2) ? sA2 : sB2;
    float* dst = ws + (size_t)blockIdx.x * 4096;
    __shared__ float tot[256];
    int t = threadIdx.x;
    float loc[16];
    float prod = 1.f;
#pragma unroll
    for (int k = 0; k < 16; ++k) {
        int idx = t * 16 + k;
        float e = (idx == 0) ? 1.f : src[idx - 1];
        prod *= e;
        loc[k] = prod;
    }
    tot[t] = prod;
    __syncthreads();
    for (int off = 1; off < 256; off <<= 1) {
        float v = (t >= off) ? tot[t - off] : 1.f;
        __syncthreads();
        tot[t] *= v;
        __syncthreads();
    }
    float excl = (t == 0) ? 1.f : tot[t - 1];
#pragma unroll
    for (int k = 0; k < 16; ++k) dst[t * 16 + k] = excl * loc[k];
}

// ---------------------------------------------------------------------------
// Elementwise prep: q1=H1/d1, gp1=G1/c1, q2=H2/d2, gp2=G2/c2, p1=x*d1[:1024]
__global__ void prep_kernel(const float* __restrict__ x, const float* __restrict__ G1,
                            const float* __restrict__ H1, const float* __restrict__ G2,
                            const float* __restrict__ H2, float* __restrict__ ws) {
    const float* c1 = ws + WS_C1;
    const float* d1 = ws + WS_D1;
    const float* c2 = ws + WS_C2;
    const float* d2 = ws + WS_D2;
    int idx = blockIdx.x * 256 + threadIdx.x;
    const int E1 = R1 * NFULL;            // 196608
    const int E2 = R2 * NFULL;            // 65536
    if (idx < E1) {
        int k = idx & (NFULL - 1);
        ws[WS_Q1 + idx] = H1[idx] / d1[k];
    } else if (idx < 2 * E1) {
        int j = idx - E1;
        int k = j & (NFULL - 1);
        ws[WS_GP1 + j] = G1[j] / c1[k];
    } else if (idx < 2 * E1 + E2) {
        int j = idx - 2 * E1;
        int k = j & (NFULL - 1);
        ws[WS_Q2 + j] = H2[j] / d2[k];
    } else if (idx < 2 * E1 + 2 * E2) {
        int j = idx - 2 * E1 - E2;
        int k = j & (NFULL - 1);
        ws[WS_GP2 + j] = G2[j] / c2[k];
    } else if (idx < 2 * E1 + 2 * E2 + BATCH * NIN) {
        int j = idx - 2 * E1 - 2 * E2;
        int m = j & (NIN - 1);
        ws[WS_P1 + j] = x[j] * d1[m];
    }
}

// ---------------------------------------------------------------------------
// Rank-K outer-product GEMM: C[m][n] = sum_r A[r*ld + m0+m] * B[r*ld + n0+n]
__global__ void gemm_rank_kernel(const float* __restrict__ A, const float* __restrict__ B,
                                 float* __restrict__ C, int Mo, int No, int Kr, int ld) {
    __shared__ float As[48 * 64];
    __shared__ float Bs[48 * 64];
    int tid = threadIdx.x;
    int tx = tid & 15, ty = tid >> 4;
    int n0 = blockIdx.x * 64;
    int m0 = blockIdx.y * 64;
    int tot = Kr * 64;
    for (int lin = tid; lin < tot; lin += 256) {
        int r = lin >> 6, i = lin & 63;
        As[lin] = A[r * ld + m0 + i];
        Bs[lin] = B[r * ld + n0 + i];
    }
    __syncthreads();
    float acc[4][4] = {};
    for (int r = 0; r < Kr; ++r) {
        float a4[4], b4[4];
#pragma unroll
        for (int i = 0; i < 4; ++i) a4[i] = As[r * 64 + ty * 4 + i];
#pragma unroll
        for (int j = 0; j < 4; ++j) b4[j] = Bs[r * 64 + tx * 4 + j];
#pragma unroll
        for (int i = 0; i < 4; ++i)
#pragma unroll
            for (int j = 0; j < 4; ++j) acc[i][j] += a4[i] * b4[j];
    }
#pragma unroll
    for (int i = 0; i < 4; ++i) {
        int m = m0 + ty * 4 + i;
#pragma unroll
        for (int j = 0; j < 4; ++j) {
            C[(size_t)m * No + n0 + tx * 4 + j] = acc[i][j];
        }
    }
}

// ---------------------------------------------------------------------------
// Chunked diagonal prefix sum, phase 1 (both matrices in one launch).
__global__ void diag_scan_p1(float* __restrict__ ws) {
    const int which = blockIdx.z;
    float* P        = ws + (which == 0 ? WS_PT1 : WS_P2M);
    float* ctot     = ws + (which == 0 ? WS_CT1 : WS_CT2);
    const int R     = which == 0 ? NIN : FCDIM;
    const int CH    = which == 0 ? CH1 : CH2;
    const int nd    = R + NFULL - 1;
    const int ctld  = which == 0 ? 5120 : 4608;
    int t = blockIdx.x * 256 + threadIdx.x;
    if (t >= nd) return;
    int doff = t - (R - 1);
    int z = blockIdx.y;
    int m0 = z * CH;
    int mlo = max(m0, -doff);
    int mhi = min(m0 + CH, min(NFULL - doff, R));
    float run = 0.f;
    if (mlo < mhi) {
        float* p = P + (size_t)mlo * NFULL + (mlo + doff);
        const size_t step = NFULL + 1;
        int len = mhi - mlo;
        int s = 0;
        for (; s + 8 <= len; s += 8) {
            float v[8];
#pragma unroll
            for (int u = 0; u < 8; ++u) v[u] = p[u * step];
#pragma unroll
            for (int u = 0; u < 8; ++u) { run += v[u]; v[u] = run; }
#pragma unroll
            for (int u = 0; u < 8; ++u) p[u * step] = v[u];
            p += 8 * step;
        }
        for (; s < len; ++s) { float v = *p; run += v; *p = run; p += step; }
    }
    ctot[(size_t)z * ctld + t] = run;
}

// Phase 2: chunk z (1..NCH-1) adds exclusive prefix of earlier chunk totals.
__global__ void diag_scan_p2(float* __restrict__ ws) {
    const int which = blockIdx.z;
    float* P        = ws + (which == 0 ? WS_PT1 : WS_P2M);
    const float* ctot = ws + (which == 0 ? WS_CT1 : WS_CT2);
    const int R     = which == 0 ? NIN : FCDIM;
    const int CH    = which == 0 ? CH1 : CH2;
    const int nd    = R + NFULL - 1;
    const int ctld  = which == 0 ? 5120 : 4608;
    int t = blockIdx.x * 256 + threadIdx.x;
    if (t >= nd) return;
    int z = blockIdx.y + 1;
    float off = 0.f;
    for (int zz = 0; zz < z; ++zz) off += ctot[(size_t)zz * ctld + t];
    if (off == 0.f) return;
    int doff = t - (R - 1);
    int m0 = z * CH;
    int mlo = max(m0, -doff);
    int mhi = min(m0 + CH, min(NFULL - doff, R));
    if (mlo >= mhi) return;
    float* p = P + (size_t)mlo * NFULL + (mlo + doff);
    const size_t step = NFULL + 1;
    int len = mhi - mlo;
    int s = 0;
    for (; s + 8 <= len; s += 8) {
        float v[8];
#pragma unroll
        for (int u = 0; u < 8; ++u) v[u] = p[u * step];
#pragma unroll
        for (int u = 0; u < 8; ++u) v[u] += off;
#pragma unroll
        for (int u = 0; u < 8; ++u) p[u * step] = v[u];
        p += 8 * step;
    }
    for (; s < len; ++s) { *p += off; p += step; }
}

// ---------------------------------------------------------------------------
// Layer-1 GEMM2 partials: 512 threads = 2 K-subgroups of 4 waves, 64x64 tile,
// 4x4 acc/thread, float4 LDS reads. In-block reduce over subgroups, then one
// partial slice per blockIdx.z. vpA = slice0 (p2 region), vpB = slice1.
__global__ void __launch_bounds__(512)
gemm2_l1_kernel(const float* __restrict__ p1, const float* __restrict__ Mt1,
                float* __restrict__ vpA, float* __restrict__ vpB) {
    __shared__ float As[2][32][68];
    __shared__ float Bs[2][32][68];
    int tid = threadIdx.x;
    int g = tid >> 8;          // K-subgroup 0/1
    int t = tid & 255;
    int tx = t & 15, ty = t >> 4;
    int n0 = blockIdx.x * 64;
    int m0 = blockIdx.y * 64;
    int kbase = blockIdx.z * 512 + g * 256;
    float acc[4][4] = {};
    for (int k0 = kbase; k0 < kbase + 256; k0 += 32) {
#pragma unroll
        for (int l = 0; l < 2; ++l) {              // A: 64x32, transpose into LDS
            int lin = t + l * 256;                 // 0..511
            int m = lin >> 3, k4 = lin & 7;
            float4 v = *(const float4*)&p1[(size_t)(m0 + m) * NIN + k0 + k4 * 4];
            As[g][k4 * 4 + 0][m] = v.x;
            As[g][k4 * 4 + 1][m] = v.y;
            As[g][k4 * 4 + 2][m] = v.z;
            As[g][k4 * 4 + 3][m] = v.w;
        }
#pragma unroll
        for (int l = 0; l < 2; ++l) {              // B: 32x64, direct
            int lin = t + l * 256;
            int k = lin >> 4, n4 = lin & 15;
            *(float4*)&Bs[g][k][n4 * 4] =
                *(const float4*)&Mt1[(size_t)(k0 + k) * NFULL + n0 + n4 * 4];
        }
        __syncthreads();
#pragma unroll
        for (int kk = 0; kk < 32; ++kk) {
            float4 a4 = *(const float4*)&As[g][kk][ty * 4];
            float4 b4 = *(const float4*)&Bs[g][kk][tx * 4];
            acc[0][0] += a4.x * b4.x; acc[0][1] += a4.x * b4.y;
            acc[0][2] += a4.x * b4.z; acc[0][3] += a4.x * b4.w;
            acc[1][0] += a4.y * b4.x; acc[1][1] += a4.y * b4.y;
            acc[1][2] += a4.y * b4.z; acc[1][3] += a4.y * b4.w;
            acc[2][0] += a4.z * b4.x; acc[2][1] += a4.z * b4.y;
            acc[2][2] += a4.z * b4.z; acc[2][3] += a4.z * b4.w;
            acc[3][0] += a4.w * b4.x; acc[3][1] += a4.w * b4.y;
            acc[3][2] += a4.w * b4.z; acc[3][3] += a4.w * b4.w;
        }
        __syncthreads();
    }
    // in-block reduce: group 1 -> LDS, group 0 adds and stores the partial
    float* red = &As[0][0][0];                     // 4352 floats >= 4096
    if (g == 1) {
#pragma unroll
        for (int i = 0; i < 4; ++i)
            *(float4*)&red[(ty * 4 + i) * 64 + tx * 4] =
                make_float4(acc[i][0], acc[i][1], acc[i][2], acc[i][3]);
    }
    __syncthreads();
    if (g == 0) {
        float* dst = (blockIdx.z == 0) ? vpA : vpB;
#pragma unroll
        for (int i = 0; i < 4; ++i) {
            int m = m0 + ty * 4 + i;
            float4 r = *(const float4*)&red[(ty * 4 + i) * 64 + tx * 4];
            *(float4*)&dst[(size_t)m * NFULL + n0 + tx * 4] =
                make_float4(acc[i][0] + r.x, acc[i][1] + r.y,
                            acc[i][2] + r.z, acc[i][3] + r.w);
        }
    }
}

// reduce + epilogue: p2 = relu(c1*(vpA+vpB) + b1) * d2  (in place over vpA)
__global__ void reduce_l1_kernel(float* __restrict__ vpA, const float* __restrict__ vpB,
                                 const float* __restrict__ c1, const float* __restrict__ b1,
                                 const float* __restrict__ d2, float* __restrict__ p2) {
    int idx4 = blockIdx.x * 256 + threadIdx.x;     // 131072 float4s
    int base = idx4 * 4;
    int n = base & (NFULL - 1);
    float4 a = *(const float4*)&vpA[base];
    float4 b = *(const float4*)&vpB[base];
    float4 cc = *(const float4*)&c1[n];
    float4 bb = *(const float4*)&b1[n];
    float4 dd = *(const float4*)&d2[n];
    float4 o;
    o.x = fmaxf(cc.x * (a.x + b.x) + bb.x, 0.f) * dd.x;
    o.y = fmaxf(cc.y * (a.y + b.y) + bb.y, 0.f) * dd.y;
    o.z = fmaxf(cc.z * (a.z + b.z) + bb.z, 0.f) * dd.z;
    o.w = fmaxf(cc.w * (a.w + b.w) + bb.w, 0.f) * dd.w;
    *(float4*)&p2[base] = o;
}

// ---------------------------------------------------------------------------
// Layer-2 GEMM2 partials (split-K=32, K-chunk 128): 256 threads, 64x64 tile,
// 4x4 acc/thread. B = M2 [n][k] transposed into LDS. vp layout [z][128][512].
__global__ void gemm2_l2_kernel(const float* __restrict__ p2, const float* __restrict__ M2,
                                float* __restrict__ vp) {
    __shared__ float As[32][68];
    __shared__ float Bs[32][68];
    int t = threadIdx.x;
    int tx = t & 15, ty = t >> 4;
    int n0 = blockIdx.x * 64;
    int m0 = blockIdx.y * 64;
    int kbase = blockIdx.z * 128;
    float acc[4][4] = {};
    for (int k0 = kbase; k0 < kbase + 128; k0 += 32) {
#pragma unroll
        for (int l = 0; l < 2; ++l) {              // A: p2 64x32, transpose
            int lin = t + l * 256;
            int m = lin >> 3, k4 = lin & 7;
            float4 v = *(const float4*)&p2[(size_t)(m0 + m) * NFULL + k0 + k4 * 4];
            As[k4 * 4 + 0][m] = v.x;
            As[k4 * 4 + 1][m] = v.y;
            As[k4 * 4 + 2][m] = v.z;
            As[k4 * 4 + 3][m] = v.w;
        }
#pragma unroll
        for (int l = 0; l < 2; ++l) {              // B: M2 [n][k] 64x32, transpose
            int lin = t + l * 256;
            int n = lin >> 3, k4 = lin & 7;
            float4 v = *(const float4*)&M2[(size_t)(n0 + n) * NFULL + k0 + k4 * 4];
            Bs[k4 * 4 + 0][n] = v.x;
            Bs[k4 * 4 + 1][n] = v.y;
            Bs[k4 * 4 + 2][n] = v.z;
            Bs[k4 * 4 + 3][n] = v.w;
        }
        __syncthreads();
#pragma unroll
        for (int kk = 0; kk < 32; ++kk) {
            float4 a4 = *(const float4*)&As[kk][ty * 4];
            float4 b4 = *(const float4*)&Bs[kk][tx * 4];
            acc[0][0] += a4.x * b4.x; acc[0][1] += a4.x * b4.y;
            acc[0][2] += a4.x * b4.z; acc[0][3] += a4.x * b4.w;
            acc[1][0] += a4.y * b4.x; acc[1][1] += a4.y * b4.y;
            acc[1][2] += a4.y * b4.z; acc[1][3] += a4.y * b4.w;
            acc[2][0] += a4.z * b4.x; acc[2][1] += a4.z * b4.y;
            acc[2][2] += a4.z * b4.z; acc[2][3] += a4.z * b4.w;
            acc[3][0] += a4.w * b4.x; acc[3][1] += a4.w * b4.y;
            acc[3][2] += a4.w * b4.z; acc[3][3] += a4.w * b4.w;
        }
        __syncthreads();
    }
#pragma unroll
    for (int i = 0; i < 4; ++i) {
        int m = m0 + ty * 4 + i;
        *(float4*)&vp[((size_t)blockIdx.z * BATCH + m) * FCDIM + n0 + tx * 4] =
            make_float4(acc[i][0], acc[i][1], acc[i][2], acc[i][3]);
    }
}

// reduce + epilogue: h2 = relu(c2 * sum_z vp[z] + b2)
__global__ void reduce_l2_kernel(const float* __restrict__ vp, const float* __restrict__ c2,
                                 const float* __restrict__ b2, float* __restrict__ h2) {
    int idx4 = blockIdx.x * 256 + threadIdx.x;     // 16384 float4s
    int base = idx4 * 4;
    int i = base & (FCDIM - 1);
    float4 s = make_float4(0.f, 0.f, 0.f, 0.f);
    for (int z = 0; z < 32; ++z) {
        float4 v = *(const float4*)&vp[(size_t)z * BATCH * FCDIM + base];
        s.x += v.x; s.y += v.y; s.z += v.z; s.w += v.w;
    }
    float4 cc = *(const float4*)&c2[i];
    float4 bb = *(const float4*)&b2[i];
    float4 o;
    o.x = fmaxf(cc.x * s.x + bb.x, 0.f);
    o.y = fmaxf(cc.y * s.y + bb.y, 0.f);
    o.z = fmaxf(cc.z * s.z + bb.z, 0.f);
    o.w = fmaxf(cc.w * s.w + bb.w, 0.f);
    *(float4*)&h2[base] = o;
}

// ---------------------------------------------------------------------------
// logits[b][o] = sum_i h2[b][i] * Wl[o][i] + bl[o]; one 64-lane wave per (b,o)
__global__ void logits_kernel(const float* __restrict__ h2, const float* __restrict__ Wl,
                              const float* __restrict__ bl, float* __restrict__ out) {
    int bb = blockIdx.x / NOUT;
    int o = blockIdx.x % NOUT;
    int lane = threadIdx.x;
    float s = 0.f;
#pragma unroll
    for (int i = lane; i < FCDIM; i += 64) s += h2[(size_t)bb * FCDIM + i] * Wl[(size_t)o * FCDIM + i];
#pragma unroll
    for (int off = 32; off > 0; off >>= 1) s += __shfl_down(s, off);
    if (lane == 0) out[(size_t)bb * NOUT + o] = s + bl[o];
}

// ---------------------------------------------------------------------------
extern "C" void kernel_launch(void* const* d_in, const int* in_sizes, int n_in,
                              void* d_out, int out_size, void* d_ws, size_t ws_size,
                              hipStream_t stream) {
    const float* x   = (const float*)d_in[0];
    const float* G1  = (const float*)d_in[1];
    const float* H1  = (const float*)d_in[2];
    const float* sA1 = (const float*)d_in[3];
    const float* sB1 = (const float*)d_in[4];
    const float* b1  = (const float*)d_in[5];
    const float* G2  = (const float*)d_in[6];
    const float* H2  = (const float*)d_in[7];
    const float* sA2 = (const float*)d_in[8];
    const float* sB2 = (const float*)d_in[9];
    const float* b2  = (const float*)d_in[10];
    const float* Wl  = (const float*)d_in[11];
    const float* bl  = (const float*)d_in[12];
    float* out = (float*)d_out;
    float* ws = (float*)d_ws;
    (void)in_sizes; (void)n_in; (void)out_size; (void)ws_size;

    // 1. cumprods: c1, d1, c2, d2
    cumprod_kernel<<<4, 256, 0, stream>>>(sA1, sB1, sA2, sB2, ws);

    // 2. prep: q1, gp1, q2, gp2, p1  (655360 elements)
    prep_kernel<<<2560, 256, 0, stream>>>(x, G1, H1, G2, H2, ws);

    // 3. Rank-K GEMMs: Pt1[m][i] = sum_r q1[r,m]*gp1[r,i]  (1024 x 4096)
    gemm_rank_kernel<<<dim3(64, 16), 256, 0, stream>>>(ws + WS_Q1, ws + WS_GP1, ws + WS_PT1,
                                                       NIN, NFULL, R1, NFULL);
    //    P2[i][m] = sum_r gp2[r,i]*q2[r,m]  (512 x 4096)
    gemm_rank_kernel<<<dim3(64, 8), 256, 0, stream>>>(ws + WS_GP2, ws + WS_Q2, ws + WS_P2M,
                                                      FCDIM, NFULL, R2, NFULL);

    // 4. Diagonal scans -> Mt1, M2 (in place), chunked 2-phase, both fused
    diag_scan_p1<<<dim3(20, NCH, 2), 256, 0, stream>>>(ws);
    diag_scan_p2<<<dim3(20, NCH - 1, 2), 256, 0, stream>>>(ws);

    // 5. GEMM2 layer 1 partials (q1..gp2 region is dead now; aliased as slice1)
    gemm2_l1_kernel<<<dim3(64, 2, 2), 512, 0, stream>>>(ws + WS_P1, ws + WS_PT1,
                                                        ws + WS_P2, ws + WS_Q1);
    //    reduce + epilogue -> p2 (in place over slice0)
    reduce_l1_kernel<<<512, 256, 0, stream>>>(ws + WS_P2, ws + WS_Q1, ws + WS_C1,
                                              b1, ws + WS_D2, ws + WS_P2);

    // 6. GEMM2 layer 2 partials (Mt1 region is dead now; aliased as vp)
    gemm2_l2_kernel<<<dim3(8, 2, 32), 256, 0, stream>>>(ws + WS_P2, ws + WS_P2M, ws + WS_PT1);
    //    reduce + epilogue -> h2
    reduce_l2_kernel<<<64, 256, 0, stream>>>(ws + WS_PT1, ws + WS_C2, b2, ws + WS_H2);

    // 7. logits
    logits_kernel<<<BATCH * NOUT, 64, 0, stream>>>(ws + WS_H2, Wl, bl, out);
}

// Round 4
// 86.110 us; speedup vs baseline: 3.0039x; 1.1964x over previous
//
#include <hip/hip_runtime.h>
#include <hip/hip_bf16.h>

// Problem constants
#define BATCH 128
#define NIN   1024
#define NFULL 4096
#define R1    48
#define R2    16
#define FCDIM 512
#define NOUT  10

// Workspace layout (float offsets). End = 11,825,152 floats (~45.1 MiB).
// (ws_size ~256 MiB per observed harness poison fills.)
#define WS_C1  0
#define WS_D1  4096
#define WS_C2  8192
#define WS_D2  12288
#define WS_Q1  16384
#define WS_GP1 (WS_Q1 + R1*NFULL)        // 212992
#define WS_Q2  (WS_GP1 + R1*NFULL)       // 409600
#define WS_GP2 (WS_Q2 + R2*NFULL)        // 475136
#define WS_P1  (WS_GP2 + R2*NFULL)       // 540672
#define WS_P2  (WS_P1 + BATCH*NIN)       // 671744
#define WS_H2  (WS_P2 + BATCH*NFULL)     // 1196032 (unused now)
#define WS_PT1 (WS_H2 + BATCH*FCDIM)     // 1261568  (1024 x 4096)
#define WS_P2M (WS_PT1 + NIN*NFULL)      // 5455872  (512 x 4096)
#define WS_CT1 (WS_P2M + FCDIM*NFULL)    // 7553024  (8 x 5120 chunk totals -> OFF1)
#define WS_CT2 (WS_CT1 + 8*5120)         // 7593984  (8 x 4608 chunk totals -> OFF2)
#define WS_VP1 (WS_CT2 + 8*4608)         // 7630848  (4 x 128 x 4096 L1 partials)
#define WS_VP2 (WS_VP1 + 4*BATCH*NFULL)  // 9728000  (32 x 128 x 512 L2 partials)
#define WS_END (WS_VP2 + 32*BATCH*FCDIM) // 11825152

// Scan geometry
#define NCH 8
#define CH1 (NIN / NCH)          // 128 rows per chunk (matrix 1)
#define CH2 (FCDIM / NCH)        // 64 rows per chunk (matrix 2)
#define CTLD1 5120
#define CTLD2 4608

// ---------------------------------------------------------------------------
// Fused cumprod + elementwise prep. 160 blocks x 256 threads.
// Each block recomputes the single cumprod it needs into LDS, then writes its
// output rows: q1=H1/d1 (48), gp1=G1/c1 (48), q2=H2/d2 (16), gp2=G2/c2 (16),
// p1=x*d1 (32 blocks x 4 rows). Row-0 blocks also store c/d vectors to ws.
__global__ void __launch_bounds__(256) prep_fused(
    const float* __restrict__ x, const float* __restrict__ G1,
    const float* __restrict__ H1, const float* __restrict__ G2,
    const float* __restrict__ H2, const float* __restrict__ sA1,
    const float* __restrict__ sB1, const float* __restrict__ sA2,
    const float* __restrict__ sB2, float* __restrict__ ws) {
    __shared__ float cd[4096];
    __shared__ float tot[256];
    int b = blockIdx.x, t = threadIdx.x;
    const float* src;
    int kind, r;
    if (b < 48)       { kind = 0; r = b;       src = sB1; }   // q1 needs d1
    else if (b < 96)  { kind = 1; r = b - 48;  src = sA1; }   // gp1 needs c1
    else if (b < 112) { kind = 2; r = b - 96;  src = sB2; }   // q2 needs d2
    else if (b < 128) { kind = 3; r = b - 112; src = sA2; }   // gp2 needs c2
    else              { kind = 4; r = b - 128; src = sB1; }   // p1 needs d1
    // cumprod of [1, cumprod(src)] into cd[0..4095]
    float loc[16];
    float prod = 1.f;
#pragma unroll
    for (int u = 0; u < 16; ++u) {
        int idx = t * 16 + u;
        float e = (idx == 0) ? 1.f : src[idx - 1];
        prod *= e;
        loc[u] = prod;
    }
    tot[t] = prod;
    __syncthreads();
    for (int off = 1; off < 256; off <<= 1) {
        float v = (t >= off) ? tot[t - off] : 1.f;
        __syncthreads();
        tot[t] *= v;
        __syncthreads();
    }
    float excl = (t == 0) ? 1.f : tot[t - 1];
#pragma unroll
    for (int u = 0; u < 16; ++u) cd[t * 16 + u] = excl * loc[u];
    __syncthreads();

    if (kind == 0) {
        const float* s0 = H1 + (size_t)r * NFULL;
        float* dst = ws + WS_Q1 + (size_t)r * NFULL;
#pragma unroll
        for (int u = 0; u < 16; ++u) { int i = t + u * 256; dst[i] = s0[i] / cd[i]; }
        if (r == 0) { float* d1 = ws + WS_D1;
#pragma unroll
            for (int u = 0; u < 16; ++u) { int i = t + u * 256; d1[i] = cd[i]; } }
    } else if (kind == 1) {
        const float* s0 = G1 + (size_t)r * NFULL;
        float* dst = ws + WS_GP1 + (size_t)r * NFULL;
#pragma unroll
        for (int u = 0; u < 16; ++u) { int i = t + u * 256; dst[i] = s0[i] / cd[i]; }
        if (r == 0) { float* c1 = ws + WS_C1;
#pragma unroll
            for (int u = 0; u < 16; ++u) { int i = t + u * 256; c1[i] = cd[i]; } }
    } else if (kind == 2) {
        const float* s0 = H2 + (size_t)r * NFULL;
        float* dst = ws + WS_Q2 + (size_t)r * NFULL;
#pragma unroll
        for (int u = 0; u < 16; ++u) { int i = t + u * 256; dst[i] = s0[i] / cd[i]; }
        if (r == 0) { float* d2 = ws + WS_D2;
#pragma unroll
            for (int u = 0; u < 16; ++u) { int i = t + u * 256; d2[i] = cd[i]; } }
    } else if (kind == 3) {
        const float* s0 = G2 + (size_t)r * NFULL;
        float* dst = ws + WS_GP2 + (size_t)r * NFULL;
#pragma unroll
        for (int u = 0; u < 16; ++u) { int i = t + u * 256; dst[i] = s0[i] / cd[i]; }
        if (r == 0) { float* c2 = ws + WS_C2;
#pragma unroll
            for (int u = 0; u < 16; ++u) { int i = t + u * 256; c2[i] = cd[i]; } }
    } else {
        int row0 = r * 4;
#pragma unroll
        for (int u = 0; u < 16; ++u) {
            int lin = t + u * 256;                 // 0..4095
            int row = row0 + (lin >> 10), col = lin & 1023;
            ws[WS_P1 + (size_t)row * NIN + col] = x[(size_t)row * NIN + col] * cd[col];
        }
    }
}

// ---------------------------------------------------------------------------
// Rank-K outer-product GEMM: C[m][n] = sum_r A[r*ld + m0+m] * B[r*ld + n0+n]
__global__ void gemm_rank_kernel(const float* __restrict__ A, const float* __restrict__ B,
                                 float* __restrict__ C, int Mo, int No, int Kr, int ld) {
    __shared__ float As[48 * 64];
    __shared__ float Bs[48 * 64];
    int tid = threadIdx.x;
    int tx = tid & 15, ty = tid >> 4;
    int n0 = blockIdx.x * 64;
    int m0 = blockIdx.y * 64;
    int tot = Kr * 64;
    for (int lin = tid; lin < tot; lin += 256) {
        int r = lin >> 6, i = lin & 63;
        As[lin] = A[r * ld + m0 + i];
        Bs[lin] = B[r * ld + n0 + i];
    }
    __syncthreads();
    float acc[4][4] = {};
    for (int r = 0; r < Kr; ++r) {
        float a4[4], b4[4];
#pragma unroll
        for (int i = 0; i < 4; ++i) a4[i] = As[r * 64 + ty * 4 + i];
#pragma unroll
        for (int j = 0; j < 4; ++j) b4[j] = Bs[r * 64 + tx * 4 + j];
#pragma unroll
        for (int i = 0; i < 4; ++i)
#pragma unroll
            for (int j = 0; j < 4; ++j) acc[i][j] += a4[i] * b4[j];
    }
#pragma unroll
    for (int i = 0; i < 4; ++i) {
        int m = m0 + ty * 4 + i;
#pragma unroll
        for (int j = 0; j < 4; ++j) {
            C[(size_t)m * No + n0 + tx * 4 + j] = acc[i][j];
        }
    }
}

// ---------------------------------------------------------------------------
// Chunked diagonal prefix sum, phase 1 (both matrices in one launch).
// Leaves each chunk's LOCAL prefix in place and stores chunk totals in ctot.
__global__ void diag_scan_p1(float* __restrict__ ws) {
    const int which = blockIdx.z;
    float* P        = ws + (which == 0 ? WS_PT1 : WS_P2M);
    float* ctot     = ws + (which == 0 ? WS_CT1 : WS_CT2);
    const int R     = which == 0 ? NIN : FCDIM;
    const int CH    = which == 0 ? CH1 : CH2;
    const int nd    = R + NFULL - 1;
    const int ctld  = which == 0 ? CTLD1 : CTLD2;
    int t = blockIdx.x * 256 + threadIdx.x;
    if (t >= nd) return;
    int doff = t - (R - 1);
    int z = blockIdx.y;
    int m0 = z * CH;
    int mlo = max(m0, -doff);
    int mhi = min(m0 + CH, min(NFULL - doff, R));
    float run = 0.f;
    if (mlo < mhi) {
        float* p = P + (size_t)mlo * NFULL + (mlo + doff);
        const size_t step = NFULL + 1;
        int len = mhi - mlo;
        int s = 0;
        for (; s + 8 <= len; s += 8) {
            float v[8];
#pragma unroll
            for (int u = 0; u < 8; ++u) v[u] = p[u * step];
#pragma unroll
            for (int u = 0; u < 8; ++u) { run += v[u]; v[u] = run; }
#pragma unroll
            for (int u = 0; u < 8; ++u) p[u * step] = v[u];
            p += 8 * step;
        }
        for (; s < len; ++s) { float v = *p; run += v; *p = run; p += step; }
    }
    ctot[(size_t)z * ctld + t] = run;
}

// In-place exclusive prefix over z of the chunk totals: ctot -> OFF.
__global__ void off_prefix(float* __restrict__ ws) {
    const int which = blockIdx.z;
    float* ct      = ws + (which == 0 ? WS_CT1 : WS_CT2);
    const int ctld = which == 0 ? CTLD1 : CTLD2;
    int t = blockIdx.x * 256 + threadIdx.x;
    if (t >= ctld) return;
    float run = 0.f;
#pragma unroll
    for (int z = 0; z < NCH; ++z) {
        float v = ct[(size_t)z * ctld + t];
        ct[(size_t)z * ctld + t] = run;
        run += v;
    }
}

// ---------------------------------------------------------------------------
// Layer-1 GEMM2 partials (split-K=4 blocks x 2 in-block groups, K-chunk 128):
// 512 threads, 64x64 tile, 4x4 acc/thread. B elements are finalized on the
// fly: Mt1_final[k][n] = Mt1_local[k][n] + OFF1[k>>7][1023 + n - k].
__global__ void __launch_bounds__(512)
gemm2_l1_kernel(const float* __restrict__ p1, const float* __restrict__ Mt1,
                const float* __restrict__ OFF1, float* __restrict__ vp) {
    __shared__ float As[2][32][68];
    __shared__ float Bs[2][32][68];
    int tid = threadIdx.x;
    int g = tid >> 8;          // K-subgroup 0/1
    int t = tid & 255;
    int tx = t & 15, ty = t >> 4;
    int n0 = blockIdx.x * 64;
    int m0 = blockIdx.y * 64;
    int kbase = blockIdx.z * 256 + g * 128;
    const float* offrow = OFF1 + (size_t)(kbase >> 7) * CTLD1;   // chunk const per group
    float acc[4][4] = {};
    for (int k0 = kbase; k0 < kbase + 128; k0 += 32) {
#pragma unroll
        for (int l = 0; l < 2; ++l) {              // A: 64x32, transpose into LDS
            int lin = t + l * 256;                 // 0..511
            int m = lin >> 3, k4 = lin & 7;
            float4 v = *(const float4*)&p1[(size_t)(m0 + m) * NIN + k0 + k4 * 4];
            As[g][k4 * 4 + 0][m] = v.x;
            As[g][k4 * 4 + 1][m] = v.y;
            As[g][k4 * 4 + 2][m] = v.z;
            As[g][k4 * 4 + 3][m] = v.w;
        }
#pragma unroll
        for (int l = 0; l < 2; ++l) {              // B: 32x64, direct + OFF fold
            int lin = t + l * 256;
            int k = lin >> 4, n4 = lin & 15;
            float4 v = *(const float4*)&Mt1[(size_t)(k0 + k) * NFULL + n0 + n4 * 4];
            const float* o = &offrow[1023 + n0 + n4 * 4 - (k0 + k)];
            v.x += o[0]; v.y += o[1]; v.z += o[2]; v.w += o[3];
            *(float4*)&Bs[g][k][n4 * 4] = v;
        }
        __syncthreads();
#pragma unroll
        for (int kk = 0; kk < 32; ++kk) {
            float4 a4 = *(const float4*)&As[g][kk][ty * 4];
            float4 b4 = *(const float4*)&Bs[g][kk][tx * 4];
            acc[0][0] += a4.x * b4.x; acc[0][1] += a4.x * b4.y;
            acc[0][2] += a4.x * b4.z; acc[0][3] += a4.x * b4.w;
            acc[1][0] += a4.y * b4.x; acc[1][1] += a4.y * b4.y;
            acc[1][2] += a4.y * b4.z; acc[1][3] += a4.y * b4.w;
            acc[2][0] += a4.z * b4.x; acc[2][1] += a4.z * b4.y;
            acc[2][2] += a4.z * b4.z; acc[2][3] += a4.z * b4.w;
            acc[3][0] += a4.w * b4.x; acc[3][1] += a4.w * b4.y;
            acc[3][2] += a4.w * b4.z; acc[3][3] += a4.w * b4.w;
        }
        __syncthreads();
    }
    // in-block reduce: group 1 -> LDS, group 0 adds and stores the partial
    float* red = &As[0][0][0];                     // 4352 floats >= 4096
    if (g == 1) {
#pragma unroll
        for (int i = 0; i < 4; ++i)
            *(float4*)&red[(ty * 4 + i) * 64 + tx * 4] =
                make_float4(acc[i][0], acc[i][1], acc[i][2], acc[i][3]);
    }
    __syncthreads();
    if (g == 0) {
        float* dst = vp + (size_t)blockIdx.z * BATCH * NFULL;
#pragma unroll
        for (int i = 0; i < 4; ++i) {
            int m = m0 + ty * 4 + i;
            float4 r = *(const float4*)&red[(ty * 4 + i) * 64 + tx * 4];
            *(float4*)&dst[(size_t)m * NFULL + n0 + tx * 4] =
                make_float4(acc[i][0] + r.x, acc[i][1] + r.y,
                            acc[i][2] + r.z, acc[i][3] + r.w);
        }
    }
}

// reduce + epilogue: p2 = relu(c1*(sum of 4 partials) + b1) * d2
__global__ void reduce_l1_kernel(const float* __restrict__ vp, const float* __restrict__ c1,
                                 const float* __restrict__ b1, const float* __restrict__ d2,
                                 float* __restrict__ p2) {
    int idx4 = blockIdx.x * 256 + threadIdx.x;     // 131072 float4s
    int base = idx4 * 4;
    int n = base & (NFULL - 1);
    float4 s = make_float4(0.f, 0.f, 0.f, 0.f);
#pragma unroll
    for (int z = 0; z < 4; ++z) {
        float4 v = *(const float4*)&vp[(size_t)z * BATCH * NFULL + base];
        s.x += v.x; s.y += v.y; s.z += v.z; s.w += v.w;
    }
    float4 cc = *(const float4*)&c1[n];
    float4 bb = *(const float4*)&b1[n];
    float4 dd = *(const float4*)&d2[n];
    float4 o;
    o.x = fmaxf(cc.x * s.x + bb.x, 0.f) * dd.x;
    o.y = fmaxf(cc.y * s.y + bb.y, 0.f) * dd.y;
    o.z = fmaxf(cc.z * s.z + bb.z, 0.f) * dd.z;
    o.w = fmaxf(cc.w * s.w + bb.w, 0.f) * dd.w;
    *(float4*)&p2[base] = o;
}

// ---------------------------------------------------------------------------
// Layer-2 GEMM2 partials (split-K=32, K-chunk 128): 256 threads, 64x64 tile.
// B = M2 [n][k] transposed into LDS with OFF2 fold:
// M2_final[i][m] = M2_local[i][m] + OFF2[i>>6][511 + m - i]   (i = n-axis here)
__global__ void gemm2_l2_kernel(const float* __restrict__ p2, const float* __restrict__ M2,
                                const float* __restrict__ OFF2, float* __restrict__ vp) {
    __shared__ float As[32][68];
    __shared__ float Bs[32][68];
    int t = threadIdx.x;
    int tx = t & 15, ty = t >> 4;
    int n0 = blockIdx.x * 64;
    int m0 = blockIdx.y * 64;
    int kbase = blockIdx.z * 128;
    const float* offrow = OFF2 + (size_t)(n0 >> 6) * CTLD2;      // chunk const per block
    float acc[4][4] = {};
    for (int k0 = kbase; k0 < kbase + 128; k0 += 32) {
#pragma unroll
        for (int l = 0; l < 2; ++l) {              // A: p2 64x32, transpose
            int lin = t + l * 256;
            int m = lin >> 3, k4 = lin & 7;
            float4 v = *(const float4*)&p2[(size_t)(m0 + m) * NFULL + k0 + k4 * 4];
            As[k4 * 4 + 0][m] = v.x;
            As[k4 * 4 + 1][m] = v.y;
            As[k4 * 4 + 2][m] = v.z;
            As[k4 * 4 + 3][m] = v.w;
        }
#pragma unroll
        for (int l = 0; l < 2; ++l) {              // B: M2 [n][k] 64x32, transpose + OFF
            int lin = t + l * 256;
            int n = lin >> 3, k4 = lin & 7;
            float4 v = *(const float4*)&M2[(size_t)(n0 + n) * NFULL + k0 + k4 * 4];
            const float* o = &offrow[511 + k0 + k4 * 4 - (n0 + n)];
            v.x += o[0]; v.y += o[1]; v.z += o[2]; v.w += o[3];
            Bs[k4 * 4 + 0][n] = v.x;
            Bs[k4 * 4 + 1][n] = v.y;
            Bs[k4 * 4 + 2][n] = v.z;
            Bs[k4 * 4 + 3][n] = v.w;
        }
        __syncthreads();
#pragma unroll
        for (int kk = 0; kk < 32; ++kk) {
            float4 a4 = *(const float4*)&As[kk][ty * 4];
            float4 b4 = *(const float4*)&Bs[kk][tx * 4];
            acc[0][0] += a4.x * b4.x; acc[0][1] += a4.x * b4.y;
            acc[0][2] += a4.x * b4.z; acc[0][3] += a4.x * b4.w;
            acc[1][0] += a4.y * b4.x; acc[1][1] += a4.y * b4.y;
            acc[1][2] += a4.y * b4.z; acc[1][3] += a4.y * b4.w;
            acc[2][0] += a4.z * b4.x; acc[2][1] += a4.z * b4.y;
            acc[2][2] += a4.z * b4.z; acc[2][3] += a4.z * b4.w;
            acc[3][0] += a4.w * b4.x; acc[3][1] += a4.w * b4.y;
            acc[3][2] += a4.w * b4.z; acc[3][3] += a4.w * b4.w;
        }
        __syncthreads();
    }
#pragma unroll
    for (int i = 0; i < 4; ++i) {
        int m = m0 + ty * 4 + i;
        *(float4*)&vp[((size_t)blockIdx.z * BATCH + m) * FCDIM + n0 + tx * 4] =
            make_float4(acc[i][0], acc[i][1], acc[i][2], acc[i][3]);
    }
}

// ---------------------------------------------------------------------------
// Fused L2 reduce + epilogue + logits. One block per batch row.
// h2[b][:] = relu(c2*sum_z vp[z][b][:] + b2) in LDS, then 10 wave-parallel dots.
__global__ void fused_out_kernel(const float* __restrict__ vp, const float* __restrict__ c2,
                                 const float* __restrict__ b2, const float* __restrict__ Wl,
                                 const float* __restrict__ bl, float* __restrict__ out) {
    __shared__ float h2s[FCDIM];
    int b = blockIdx.x, t = threadIdx.x;
    for (int col = t; col < FCDIM; col += 256) {
        float s = 0.f;
#pragma unroll
        for (int z = 0; z < 32; ++z)
            s += vp[((size_t)z * BATCH + b) * FCDIM + col];
        h2s[col] = fmaxf(c2[col] * s + b2[col], 0.f);
    }
    __syncthreads();
    int w = t >> 6, lane = t & 63;
    for (int o = w; o < NOUT; o += 4) {
        float s = 0.f;
#pragma unroll
        for (int i = lane; i < FCDIM; i += 64) s += h2s[i] * Wl[(size_t)o * FCDIM + i];
#pragma unroll
        for (int off = 32; off > 0; off >>= 1) s += __shfl_down(s, off);
        if (lane == 0) out[(size_t)b * NOUT + o] = s + bl[o];
    }
}

// ---------------------------------------------------------------------------
extern "C" void kernel_launch(void* const* d_in, const int* in_sizes, int n_in,
                              void* d_out, int out_size, void* d_ws, size_t ws_size,
                              hipStream_t stream) {
    const float* x   = (const float*)d_in[0];
    const float* G1  = (const float*)d_in[1];
    const float* H1  = (const float*)d_in[2];
    const float* sA1 = (const float*)d_in[3];
    const float* sB1 = (const float*)d_in[4];
    const float* b1  = (const float*)d_in[5];
    const float* G2  = (const float*)d_in[6];
    const float* H2  = (const float*)d_in[7];
    const float* sA2 = (const float*)d_in[8];
    const float* sB2 = (const float*)d_in[9];
    const float* b2  = (const float*)d_in[10];
    const float* Wl  = (const float*)d_in[11];
    const float* bl  = (const float*)d_in[12];
    float* out = (float*)d_out;
    float* ws = (float*)d_ws;
    (void)in_sizes; (void)n_in; (void)out_size; (void)ws_size;

    // 1. fused cumprod + prep: c/d vectors, q1, gp1, q2, gp2, p1
    prep_fused<<<160, 256, 0, stream>>>(x, G1, H1, G2, H2, sA1, sB1, sA2, sB2, ws);

    // 2. Rank-K GEMMs: Pt1[m][i] = sum_r q1[r,m]*gp1[r,i]  (1024 x 4096)
    gemm_rank_kernel<<<dim3(64, 16), 256, 0, stream>>>(ws + WS_Q1, ws + WS_GP1, ws + WS_PT1,
                                                       NIN, NFULL, R1, NFULL);
    //    P2[i][m] = sum_r gp2[r,i]*q2[r,m]  (512 x 4096)
    gemm_rank_kernel<<<dim3(64, 8), 256, 0, stream>>>(ws + WS_GP2, ws + WS_Q2, ws + WS_P2M,
                                                      FCDIM, NFULL, R2, NFULL);

    // 3. Chunk-local diagonal scans (in place) + chunk totals
    diag_scan_p1<<<dim3(20, NCH, 2), 256, 0, stream>>>(ws);
    //    chunk totals -> exclusive offsets (in place)
    off_prefix<<<dim3(20, 1, 2), 256, 0, stream>>>(ws);

    // 4. GEMM2 layer 1 (OFF fold during staging) -> 4 partial slices
    gemm2_l1_kernel<<<dim3(64, 2, 4), 512, 0, stream>>>(ws + WS_P1, ws + WS_PT1,
                                                        ws + WS_CT1, ws + WS_VP1);
    //    reduce + epilogue -> p2
    reduce_l1_kernel<<<512, 256, 0, stream>>>(ws + WS_VP1, ws + WS_C1, b1, ws + WS_D2,
                                              ws + WS_P2);

    // 5. GEMM2 layer 2 (OFF fold during staging, split-K=32) -> partials
    gemm2_l2_kernel<<<dim3(8, 2, 32), 256, 0, stream>>>(ws + WS_P2, ws + WS_P2M,
                                                        ws + WS_CT2, ws + WS_VP2);

    // 6. fused reduce + epilogue + logits
    fused_out_kernel<<<BATCH, 256, 0, stream>>>(ws + WS_VP2, ws + WS_C2, b2, Wl, bl, out);
}

// Round 5
// 79.893 us; speedup vs baseline: 3.2377x; 1.0778x over previous
//
#include <hip/hip_runtime.h>
#include <hip/hip_bf16.h>

// Problem constants
#define BATCH 128
#define NIN   1024
#define NFULL 4096
#define R1    48
#define R2    16
#define FCDIM 512
#define NOUT  10

// Workspace layout (float offsets). End = 11,866,112 floats (~45.3 MiB).
#define WS_C1  0
#define WS_D1  4096
#define WS_C2  8192
#define WS_D2  12288
#define WS_Q1  16384
#define WS_GP1 (WS_Q1 + R1*NFULL)        // 212992
#define WS_Q2  (WS_GP1 + R1*NFULL)       // 409600
#define WS_GP2 (WS_Q2 + R2*NFULL)        // 475136
#define WS_P1  (WS_GP2 + R2*NFULL)       // 540672
#define WS_P2  (WS_P1 + BATCH*NIN)       // 671744
#define WS_H2  (WS_P2 + BATCH*NFULL)     // 1196032 (spare)
#define WS_PT1 (WS_H2 + BATCH*FCDIM)     // 1261568  (1024 x 4096)
#define WS_P2M (WS_PT1 + NIN*NFULL)      // 5455872  (512 x 4096)
#define WS_CT1 (WS_P2M + FCDIM*NFULL)    // 7553024  (16 x 5120 chunk totals -> OFF1)
#define WS_CT2 (WS_CT1 + 16*5120)        // 7634944  (8 x 4608 chunk totals -> OFF2)
#define WS_VP1 (WS_CT2 + 8*4608)         // 7671808  (4 x 128 x 4096 L1 partials)
#define WS_VP2 (WS_VP1 + 4*BATCH*NFULL)  // 9768960  (32 x 128 x 512 L2 partials)
#define WS_END (WS_VP2 + 32*BATCH*FCDIM) // 11866112

// Scan geometry: both matrices use 64-row chunks.
#define NCH1 16
#define NCH2 8
#define CHROWS 64
#define CTLD1 5120
#define CTLD2 4608

// ---------------------------------------------------------------------------
// Fused cumprod + elementwise prep. 160 blocks x 256 threads.
__global__ void __launch_bounds__(256) prep_fused(
    const float* __restrict__ x, const float* __restrict__ G1,
    const float* __restrict__ H1, const float* __restrict__ G2,
    const float* __restrict__ H2, const float* __restrict__ sA1,
    const float* __restrict__ sB1, const float* __restrict__ sA2,
    const float* __restrict__ sB2, float* __restrict__ ws) {
    __shared__ float cd[4096];
    __shared__ float tot[256];
    int b = blockIdx.x, t = threadIdx.x;
    const float* src;
    int kind, r;
    if (b < 48)       { kind = 0; r = b;       src = sB1; }   // q1 needs d1
    else if (b < 96)  { kind = 1; r = b - 48;  src = sA1; }   // gp1 needs c1
    else if (b < 112) { kind = 2; r = b - 96;  src = sB2; }   // q2 needs d2
    else if (b < 128) { kind = 3; r = b - 112; src = sA2; }   // gp2 needs c2
    else              { kind = 4; r = b - 128; src = sB1; }   // p1 needs d1
    float loc[16];
    float prod = 1.f;
#pragma unroll
    for (int u = 0; u < 16; ++u) {
        int idx = t * 16 + u;
        float e = (idx == 0) ? 1.f : src[idx - 1];
        prod *= e;
        loc[u] = prod;
    }
    tot[t] = prod;
    __syncthreads();
    for (int off = 1; off < 256; off <<= 1) {
        float v = (t >= off) ? tot[t - off] : 1.f;
        __syncthreads();
        tot[t] *= v;
        __syncthreads();
    }
    float excl = (t == 0) ? 1.f : tot[t - 1];
#pragma unroll
    for (int u = 0; u < 16; ++u) cd[t * 16 + u] = excl * loc[u];
    __syncthreads();

    if (kind == 0) {
        const float* s0 = H1 + (size_t)r * NFULL;
        float* dst = ws + WS_Q1 + (size_t)r * NFULL;
#pragma unroll
        for (int u = 0; u < 16; ++u) { int i = t + u * 256; dst[i] = s0[i] / cd[i]; }
        if (r == 0) { float* d1 = ws + WS_D1;
#pragma unroll
            for (int u = 0; u < 16; ++u) { int i = t + u * 256; d1[i] = cd[i]; } }
    } else if (kind == 1) {
        const float* s0 = G1 + (size_t)r * NFULL;
        float* dst = ws + WS_GP1 + (size_t)r * NFULL;
#pragma unroll
        for (int u = 0; u < 16; ++u) { int i = t + u * 256; dst[i] = s0[i] / cd[i]; }
        if (r == 0) { float* c1 = ws + WS_C1;
#pragma unroll
            for (int u = 0; u < 16; ++u) { int i = t + u * 256; c1[i] = cd[i]; } }
    } else if (kind == 2) {
        const float* s0 = H2 + (size_t)r * NFULL;
        float* dst = ws + WS_Q2 + (size_t)r * NFULL;
#pragma unroll
        for (int u = 0; u < 16; ++u) { int i = t + u * 256; dst[i] = s0[i] / cd[i]; }
        if (r == 0) { float* d2 = ws + WS_D2;
#pragma unroll
            for (int u = 0; u < 16; ++u) { int i = t + u * 256; d2[i] = cd[i]; } }
    } else if (kind == 3) {
        const float* s0 = G2 + (size_t)r * NFULL;
        float* dst = ws + WS_GP2 + (size_t)r * NFULL;
#pragma unroll
        for (int u = 0; u < 16; ++u) { int i = t + u * 256; dst[i] = s0[i] / cd[i]; }
        if (r == 0) { float* c2 = ws + WS_C2;
#pragma unroll
            for (int u = 0; u < 16; ++u) { int i = t + u * 256; c2[i] = cd[i]; } }
    } else {
        int row0 = r * 4;
#pragma unroll
        for (int u = 0; u < 16; ++u) {
            int lin = t + u * 256;                 // 0..4095
            int row = row0 + (lin >> 10), col = lin & 1023;
            ws[WS_P1 + (size_t)row * NIN + col] = x[(size_t)row * NIN + col] * cd[col];
        }
    }
}

// ---------------------------------------------------------------------------
// Rank-K outer-product GEMMs, both in one launch (z: 0 = M1, 1 = M2).
// C[m][n] = sum_r A[r][m0+m] * B[r][n0+n]; tile 64x64, float4 LDS + stores.
__global__ void __launch_bounds__(256) gemm_rank_kernel(float* __restrict__ ws) {
    const int which = blockIdx.z;
    if (which == 1 && blockIdx.y >= 8) return;
    const float* A = ws + (which == 0 ? WS_Q1  : WS_GP2);
    const float* B = ws + (which == 0 ? WS_GP1 : WS_Q2);
    float* C       = ws + (which == 0 ? WS_PT1 : WS_P2M);
    const int Kr   = which == 0 ? R1 : R2;
    __shared__ float As[R1 * 68];
    __shared__ float Bs[R1 * 68];
    int tid = threadIdx.x;
    int tx = tid & 15, ty = tid >> 4;
    int n0 = blockIdx.x * 64;
    int m0 = blockIdx.y * 64;
    int nf4 = Kr * 16;
    for (int lin = tid; lin < nf4; lin += 256) {
        int r = lin >> 4, i4 = lin & 15;
        *(float4*)&As[r * 68 + i4 * 4] = *(const float4*)&A[(size_t)r * NFULL + m0 + i4 * 4];
        *(float4*)&Bs[r * 68 + i4 * 4] = *(const float4*)&B[(size_t)r * NFULL + n0 + i4 * 4];
    }
    __syncthreads();
    float acc[4][4] = {};
#pragma unroll 8
    for (int r = 0; r < Kr; ++r) {
        float4 a4 = *(const float4*)&As[r * 68 + ty * 4];
        float4 b4 = *(const float4*)&Bs[r * 68 + tx * 4];
        acc[0][0] += a4.x * b4.x; acc[0][1] += a4.x * b4.y;
        acc[0][2] += a4.x * b4.z; acc[0][3] += a4.x * b4.w;
        acc[1][0] += a4.y * b4.x; acc[1][1] += a4.y * b4.y;
        acc[1][2] += a4.y * b4.z; acc[1][3] += a4.y * b4.w;
        acc[2][0] += a4.z * b4.x; acc[2][1] += a4.z * b4.y;
        acc[2][2] += a4.z * b4.z; acc[2][3] += a4.z * b4.w;
        acc[3][0] += a4.w * b4.x; acc[3][1] += a4.w * b4.y;
        acc[3][2] += a4.w * b4.z; acc[3][3] += a4.w * b4.w;
    }
#pragma unroll
    for (int i = 0; i < 4; ++i) {
        int m = m0 + ty * 4 + i;
        *(float4*)&C[(size_t)m * NFULL + n0 + tx * 4] =
            make_float4(acc[i][0], acc[i][1], acc[i][2], acc[i][3]);
    }
}

// ---------------------------------------------------------------------------
// Chunked diagonal prefix sum, phase 1. 64-row chunks for both matrices.
// Thread t owns diagonal offset d = t-(R-1); within chunk z computes the
// chunk-local prefix in place (coalesced across lanes) + stores chunk total.
__global__ void diag_scan_p1(float* __restrict__ ws) {
    const int which = blockIdx.z;
    const int nch   = which == 0 ? NCH1 : NCH2;
    if (blockIdx.y >= (unsigned)nch) return;
    float* P        = ws + (which == 0 ? WS_PT1 : WS_P2M);
    float* ctot     = ws + (which == 0 ? WS_CT1 : WS_CT2);
    const int R     = which == 0 ? NIN : FCDIM;
    const int nd    = R + NFULL - 1;
    const int ctld  = which == 0 ? CTLD1 : CTLD2;
    int t = blockIdx.x * 256 + threadIdx.x;
    if (t >= nd) return;
    int doff = t - (R - 1);
    int z = blockIdx.y;
    int m0 = z * CHROWS;
    int mlo = max(m0, -doff);
    int mhi = min(m0 + CHROWS, min(NFULL - doff, R));
    float run = 0.f;
    if (mlo < mhi) {
        float* p = P + (size_t)mlo * NFULL + (mlo + doff);
        const size_t step = NFULL + 1;
        int len = mhi - mlo;
        int s = 0;
        for (; s + 16 <= len; s += 16) {
            float v[16];
#pragma unroll
            for (int u = 0; u < 16; ++u) v[u] = p[u * step];
#pragma unroll
            for (int u = 0; u < 16; ++u) { run += v[u]; v[u] = run; }
#pragma unroll
            for (int u = 0; u < 16; ++u) p[u * step] = v[u];
            p += 16 * step;
        }
        for (; s < len; ++s) { float v = *p; run += v; *p = run; p += step; }
    }
    ctot[(size_t)z * ctld + t] = run;
}

// In-place exclusive prefix over z of the chunk totals: ctot -> OFF.
__global__ void off_prefix(float* __restrict__ ws) {
    const int which = blockIdx.z;
    float* ct      = ws + (which == 0 ? WS_CT1 : WS_CT2);
    const int ctld = which == 0 ? CTLD1 : CTLD2;
    const int nch  = which == 0 ? NCH1 : NCH2;
    int t = blockIdx.x * 256 + threadIdx.x;
    if (t >= ctld) return;
    float run = 0.f;
    for (int z = 0; z < nch; ++z) {
        float v = ct[(size_t)z * ctld + t];
        ct[(size_t)z * ctld + t] = run;
        run += v;
    }
}

// ---------------------------------------------------------------------------
// Layer-1 GEMM2 partials. Grid (64,1,4), 1024 threads = 2 K-subgroups of 512.
// Tile 128(m=batch) x 64(n); K-chunk 128 per subgroup; 4x4 acc/thread.
// B finalized on the fly: Mt1_f[k][n] = Mt1[k][n] + OFF1[k>>6][1023 + n - k].
__global__ void __launch_bounds__(1024)
gemm2_l1_kernel(const float* __restrict__ p1, const float* __restrict__ Mt1,
                const float* __restrict__ OFF1, float* __restrict__ vp) {
    __shared__ float As[2][32][132];
    __shared__ float Bs[2][32][68];
    int tid = threadIdx.x;
    int g = tid >> 9;          // K-subgroup 0/1
    int t = tid & 511;
    int tx = t & 15, ty = t >> 4;          // ty 0..31 -> 4 m-rows each (128)
    int n0 = blockIdx.x * 64;
    int kbase = blockIdx.z * 256 + g * 128;
    float acc[4][4] = {};
    for (int k0 = kbase; k0 < kbase + 128; k0 += 32) {
        const float* orow = OFF1 + (size_t)(k0 >> 6) * CTLD1;   // const per 32-slab
#pragma unroll
        for (int l = 0; l < 2; ++l) {              // A: 128x32, transpose into LDS
            int lin = t + l * 512;                 // 0..1023
            int m = lin >> 3, k4 = lin & 7;
            float4 v = *(const float4*)&p1[(size_t)m * NIN + k0 + k4 * 4];
            As[g][k4 * 4 + 0][m] = v.x;
            As[g][k4 * 4 + 1][m] = v.y;
            As[g][k4 * 4 + 2][m] = v.z;
            As[g][k4 * 4 + 3][m] = v.w;
        }
        {                                          // B: 32x64, direct + OFF fold
            int k = t >> 4, n4 = t & 15;
            float4 v = *(const float4*)&Mt1[(size_t)(k0 + k) * NFULL + n0 + n4 * 4];
            const float* o = &orow[1023 + n0 + n4 * 4 - (k0 + k)];
            v.x += o[0]; v.y += o[1]; v.z += o[2]; v.w += o[3];
            *(float4*)&Bs[g][k][n4 * 4] = v;
        }
        __syncthreads();
#pragma unroll
        for (int kk = 0; kk < 32; ++kk) {
            float4 a4 = *(const float4*)&As[g][kk][ty * 4];
            float4 b4 = *(const float4*)&Bs[g][kk][tx * 4];
            acc[0][0] += a4.x * b4.x; acc[0][1] += a4.x * b4.y;
            acc[0][2] += a4.x * b4.z; acc[0][3] += a4.x * b4.w;
            acc[1][0] += a4.y * b4.x; acc[1][1] += a4.y * b4.y;
            acc[1][2] += a4.y * b4.z; acc[1][3] += a4.y * b4.w;
            acc[2][0] += a4.z * b4.x; acc[2][1] += a4.z * b4.y;
            acc[2][2] += a4.z * b4.z; acc[2][3] += a4.z * b4.w;
            acc[3][0] += a4.w * b4.x; acc[3][1] += a4.w * b4.y;
            acc[3][2] += a4.w * b4.z; acc[3][3] += a4.w * b4.w;
        }
        __syncthreads();
    }
    // in-block reduce: group 1 -> LDS (reuse As: 8448 >= 8192), group 0 adds.
    float* red = &As[0][0][0];
    if (g == 1) {
#pragma unroll
        for (int i = 0; i < 4; ++i)
            *(float4*)&red[(ty * 4 + i) * 64 + tx * 4] =
                make_float4(acc[i][0], acc[i][1], acc[i][2], acc[i][3]);
    }
    __syncthreads();
    if (g == 0) {
        float* dst = vp + (size_t)blockIdx.z * BATCH * NFULL;
#pragma unroll
        for (int i = 0; i < 4; ++i) {
            int m = ty * 4 + i;
            float4 r = *(const float4*)&red[m * 64 + tx * 4];
            *(float4*)&dst[(size_t)m * NFULL + n0 + tx * 4] =
                make_float4(acc[i][0] + r.x, acc[i][1] + r.y,
                            acc[i][2] + r.z, acc[i][3] + r.w);
        }
    }
}

// reduce + epilogue: p2 = relu(c1*(sum of 4 partials) + b1) * d2
__global__ void reduce_l1_kernel(const float* __restrict__ vp, const float* __restrict__ c1,
                                 const float* __restrict__ b1, const float* __restrict__ d2,
                                 float* __restrict__ p2) {
    int idx4 = blockIdx.x * 256 + threadIdx.x;     // 131072 float4s
    int base = idx4 * 4;
    int n = base & (NFULL - 1);
    float4 s = make_float4(0.f, 0.f, 0.f, 0.f);
#pragma unroll
    for (int z = 0; z < 4; ++z) {
        float4 v = *(const float4*)&vp[(size_t)z * BATCH * NFULL + base];
        s.x += v.x; s.y += v.y; s.z += v.z; s.w += v.w;
    }
    float4 cc = *(const float4*)&c1[n];
    float4 bb = *(const float4*)&b1[n];
    float4 dd = *(const float4*)&d2[n];
    float4 o;
    o.x = fmaxf(cc.x * s.x + bb.x, 0.f) * dd.x;
    o.y = fmaxf(cc.y * s.y + bb.y, 0.f) * dd.y;
    o.z = fmaxf(cc.z * s.z + bb.z, 0.f) * dd.z;
    o.w = fmaxf(cc.w * s.w + bb.w, 0.f) * dd.w;
    *(float4*)&p2[base] = o;
}

// ---------------------------------------------------------------------------
// Layer-2 GEMM2 partials. Grid (8,1,32), 512 threads. Tile 128 x 64,
// K-chunk 128. B = M2 [n][k] transposed into LDS with OFF2 fold:
// M2_f[i][m] = M2[i][m] + OFF2[i>>6][511 + m - i].
__global__ void __launch_bounds__(512)
gemm2_l2_kernel(const float* __restrict__ p2, const float* __restrict__ M2,
                const float* __restrict__ OFF2, float* __restrict__ vp) {
    __shared__ float As[32][132];
    __shared__ float Bs[32][68];
    int t = threadIdx.x;
    int tx = t & 15, ty = t >> 4;          // ty 0..31 -> 4 m-rows each (128)
    int n0 = blockIdx.x * 64;
    int kbase = blockIdx.z * 128;
    const float* offrow = OFF2 + (size_t)(n0 >> 6) * CTLD2;      // const per block
    float acc[4][4] = {};
    for (int k0 = kbase; k0 < kbase + 128; k0 += 32) {
#pragma unroll
        for (int l = 0; l < 2; ++l) {              // A: p2 128x32, transpose
            int lin = t + l * 512;
            int m = lin >> 3, k4 = lin & 7;
            float4 v = *(const float4*)&p2[(size_t)m * NFULL + k0 + k4 * 4];
            As[k4 * 4 + 0][m] = v.x;
            As[k4 * 4 + 1][m] = v.y;
            As[k4 * 4 + 2][m] = v.z;
            As[k4 * 4 + 3][m] = v.w;
        }
        {                                          // B: M2 [n][k] 64x32, transpose + OFF
            int n = t >> 3, k4 = t & 7;
            float4 v = *(const float4*)&M2[(size_t)(n0 + n) * NFULL + k0 + k4 * 4];
            const float* o = &offrow[511 + k0 + k4 * 4 - (n0 + n)];
            v.x += o[0]; v.y += o[1]; v.z += o[2]; v.w += o[3];
            Bs[k4 * 4 + 0][n] = v.x;
            Bs[k4 * 4 + 1][n] = v.y;
            Bs[k4 * 4 + 2][n] = v.z;
            Bs[k4 * 4 + 3][n] = v.w;
        }
        __syncthreads();
#pragma unroll
        for (int kk = 0; kk < 32; ++kk) {
            float4 a4 = *(const float4*)&As[kk][ty * 4];
            float4 b4 = *(const float4*)&Bs[kk][tx * 4];
            acc[0][0] += a4.x * b4.x; acc[0][1] += a4.x * b4.y;
            acc[0][2] += a4.x * b4.z; acc[0][3] += a4.x * b4.w;
            acc[1][0] += a4.y * b4.x; acc[1][1] += a4.y * b4.y;
            acc[1][2] += a4.y * b4.z; acc[1][3] += a4.y * b4.w;
            acc[2][0] += a4.z * b4.x; acc[2][1] += a4.z * b4.y;
            acc[2][2] += a4.z * b4.z; acc[2][3] += a4.z * b4.w;
            acc[3][0] += a4.w * b4.x; acc[3][1] += a4.w * b4.y;
            acc[3][2] += a4.w * b4.z; acc[3][3] += a4.w * b4.w;
        }
        __syncthreads();
    }
#pragma unroll
    for (int i = 0; i < 4; ++i) {
        int m = ty * 4 + i;
        *(float4*)&vp[((size_t)blockIdx.z * BATCH + m) * FCDIM + n0 + tx * 4] =
            make_float4(acc[i][0], acc[i][1], acc[i][2], acc[i][3]);
    }
}

// ---------------------------------------------------------------------------
// Fused L2 reduce + epilogue + logits. One block per batch row.
__global__ void fused_out_kernel(const float* __restrict__ vp, const float* __restrict__ c2,
                                 const float* __restrict__ b2, const float* __restrict__ Wl,
                                 const float* __restrict__ bl, float* __restrict__ out) {
    __shared__ float h2s[FCDIM];
    int b = blockIdx.x, t = threadIdx.x;
    for (int col = t; col < FCDIM; col += 256) {
        float s = 0.f;
#pragma unroll
        for (int z = 0; z < 32; ++z)
            s += vp[((size_t)z * BATCH + b) * FCDIM + col];
        h2s[col] = fmaxf(c2[col] * s + b2[col], 0.f);
    }
    __syncthreads();
    int w = t >> 6, lane = t & 63;
    for (int o = w; o < NOUT; o += 4) {
        float s = 0.f;
#pragma unroll
        for (int i = lane; i < FCDIM; i += 64) s += h2s[i] * Wl[(size_t)o * FCDIM + i];
#pragma unroll
        for (int off = 32; off > 0; off >>= 1) s += __shfl_down(s, off);
        if (lane == 0) out[(size_t)b * NOUT + o] = s + bl[o];
    }
}

// ---------------------------------------------------------------------------
extern "C" void kernel_launch(void* const* d_in, const int* in_sizes, int n_in,
                              void* d_out, int out_size, void* d_ws, size_t ws_size,
                              hipStream_t stream) {
    const float* x   = (const float*)d_in[0];
    const float* G1  = (const float*)d_in[1];
    const float* H1  = (const float*)d_in[2];
    const float* sA1 = (const float*)d_in[3];
    const float* sB1 = (const float*)d_in[4];
    const float* b1  = (const float*)d_in[5];
    const float* G2  = (const float*)d_in[6];
    const float* H2  = (const float*)d_in[7];
    const float* sA2 = (const float*)d_in[8];
    const float* sB2 = (const float*)d_in[9];
    const float* b2  = (const float*)d_in[10];
    const float* Wl  = (const float*)d_in[11];
    const float* bl  = (const float*)d_in[12];
    float* out = (float*)d_out;
    float* ws = (float*)d_ws;
    (void)in_sizes; (void)n_in; (void)out_size; (void)ws_size;

    // 1. fused cumprod + prep: c/d vectors, q1, gp1, q2, gp2, p1
    prep_fused<<<160, 256, 0, stream>>>(x, G1, H1, G2, H2, sA1, sB1, sA2, sB2, ws);

    // 2. Both rank-K GEMMs in one launch (z=0: Pt1 1024x4096, z=1: P2M 512x4096)
    gemm_rank_kernel<<<dim3(64, 16, 2), 256, 0, stream>>>(ws);

    // 3. Chunk-local diagonal scans (64-row chunks) + chunk totals
    diag_scan_p1<<<dim3(20, NCH1, 2), 256, 0, stream>>>(ws);
    //    chunk totals -> exclusive offsets (in place)
    off_prefix<<<dim3(20, 1, 2), 256, 0, stream>>>(ws);

    // 4. GEMM2 layer 1 (B read exactly once; OFF fold during staging) -> 4 partials
    gemm2_l1_kernel<<<dim3(64, 1, 4), 1024, 0, stream>>>(ws + WS_P1, ws + WS_PT1,
                                                         ws + WS_CT1, ws + WS_VP1);
    //    reduce + epilogue -> p2
    reduce_l1_kernel<<<512, 256, 0, stream>>>(ws + WS_VP1, ws + WS_C1, b1, ws + WS_D2,
                                              ws + WS_P2);

    // 5. GEMM2 layer 2 (B read once, split-K=32) -> partials
    gemm2_l2_kernel<<<dim3(8, 1, 32), 512, 0, stream>>>(ws + WS_P2, ws + WS_P2M,
                                                        ws + WS_CT2, ws + WS_VP2);

    // 6. fused reduce + epilogue + logits
    fused_out_kernel<<<BATCH, 256, 0, stream>>>(ws + WS_VP2, ws + WS_C2, b2, Wl, bl, out);
}

// Round 6
// 71.228 us; speedup vs baseline: 3.6315x; 1.1216x over previous
//
#include <hip/hip_runtime.h>
#include <hip/hip_bf16.h>

// Problem constants
#define BATCH 128
#define NIN   1024
#define NFULL 4096
#define R1    48
#define R2    16
#define FCDIM 512
#define NOUT  10

// Workspace layout (float offsets). End = 11,866,112 floats (~45.3 MiB).
#define WS_C1  0
#define WS_D1  4096
#define WS_C2  8192
#define WS_D2  12288
#define WS_Q1  16384
#define WS_GP1 (WS_Q1 + R1*NFULL)        // 212992
#define WS_Q2  (WS_GP1 + R1*NFULL)       // 409600
#define WS_GP2 (WS_Q2 + R2*NFULL)        // 475136
#define WS_P1  (WS_GP2 + R2*NFULL)       // 540672  (p1 hi/lo bf16 planes, 131072 f32-slots)
#define WS_P2  (WS_P1 + BATCH*NIN)       // 671744  (p2 hi/lo bf16 planes, 524288 f32-slots)
#define WS_H2  (WS_P2 + BATCH*NFULL)     // 1196032 (spare)
#define WS_PT1 (WS_H2 + BATCH*FCDIM)     // 1261568  (1024 x 4096 fp32, local-scanned P1)
#define WS_P2M (WS_PT1 + NIN*NFULL)      // 5455872  (512 x 4096 fp32, local-scanned P2)
#define WS_CT1 (WS_P2M + FCDIM*NFULL)    // 7553024  (16 x 5120 chunk totals -> OFF1)
#define WS_CT2 (WS_CT1 + 16*5120)        // 7634944  (8 x 4608 chunk totals -> OFF2)
#define WS_VP1 (WS_CT2 + 8*4608)         // 7671808  (4 x 128 x 4096 L1 partials)
#define WS_VP2 (WS_VP1 + 4*BATCH*NFULL)  // 9768960  (32 x 128 x 512 L2 partials)
#define WS_END (WS_VP2 + 32*BATCH*FCDIM) // 11866112

// Scan geometry: both matrices use 64-row chunks.
#define NCH1 16
#define NCH2 8
#define CHROWS 64
#define CTLD1 5120
#define CTLD2 4608

typedef __attribute__((ext_vector_type(8))) short bf16x8;   // 8 bf16 (raw bits)
typedef __attribute__((ext_vector_type(4))) float f32x4;

__device__ __forceinline__ unsigned short f2b(float f) {    // f32 -> bf16 bits, RNE
    unsigned u = __builtin_bit_cast(unsigned, f);
    return (unsigned short)((u + 0x7fffu + ((u >> 16) & 1u)) >> 16);
}
__device__ __forceinline__ float b2f(unsigned short h) {
    unsigned u = ((unsigned)h) << 16;
    return __builtin_bit_cast(float, u);
}
#define MFMA16(a, b, c) __builtin_amdgcn_mfma_f32_16x16x32_bf16(a, b, c, 0, 0, 0)

// ---------------------------------------------------------------------------
// Fused cumprod + elementwise prep. 160 blocks x 256 threads.
// p1 is emitted as hi/lo bf16 planes for the MFMA layer-1 GEMM.
__global__ void __launch_bounds__(256) prep_fused(
    const float* __restrict__ x, const float* __restrict__ G1,
    const float* __restrict__ H1, const float* __restrict__ G2,
    const float* __restrict__ H2, const float* __restrict__ sA1,
    const float* __restrict__ sB1, const float* __restrict__ sA2,
    const float* __restrict__ sB2, float* __restrict__ ws) {
    __shared__ float cd[4096];
    __shared__ float tot[256];
    int b = blockIdx.x, t = threadIdx.x;
    const float* src;
    int kind, r;
    if (b < 48)       { kind = 0; r = b;       src = sB1; }   // q1 needs d1
    else if (b < 96)  { kind = 1; r = b - 48;  src = sA1; }   // gp1 needs c1
    else if (b < 112) { kind = 2; r = b - 96;  src = sB2; }   // q2 needs d2
    else if (b < 128) { kind = 3; r = b - 112; src = sA2; }   // gp2 needs c2
    else              { kind = 4; r = b - 128; src = sB1; }   // p1 needs d1
    float loc[16];
    float prod = 1.f;
#pragma unroll
    for (int u = 0; u < 16; ++u) {
        int idx = t * 16 + u;
        float e = (idx == 0) ? 1.f : src[idx - 1];
        prod *= e;
        loc[u] = prod;
    }
    tot[t] = prod;
    __syncthreads();
    for (int off = 1; off < 256; off <<= 1) {
        float v = (t >= off) ? tot[t - off] : 1.f;
        __syncthreads();
        tot[t] *= v;
        __syncthreads();
    }
    float excl = (t == 0) ? 1.f : tot[t - 1];
#pragma unroll
    for (int u = 0; u < 16; ++u) cd[t * 16 + u] = excl * loc[u];
    __syncthreads();

    if (kind == 0) {
        const float* s0 = H1 + (size_t)r * NFULL;
        float* dst = ws + WS_Q1 + (size_t)r * NFULL;
#pragma unroll
        for (int u = 0; u < 16; ++u) { int i = t + u * 256; dst[i] = s0[i] / cd[i]; }
        if (r == 0) { float* d1 = ws + WS_D1;
#pragma unroll
            for (int u = 0; u < 16; ++u) { int i = t + u * 256; d1[i] = cd[i]; } }
    } else if (kind == 1) {
        const float* s0 = G1 + (size_t)r * NFULL;
        float* dst = ws + WS_GP1 + (size_t)r * NFULL;
#pragma unroll
        for (int u = 0; u < 16; ++u) { int i = t + u * 256; dst[i] = s0[i] / cd[i]; }
        if (r == 0) { float* c1 = ws + WS_C1;
#pragma unroll
            for (int u = 0; u < 16; ++u) { int i = t + u * 256; c1[i] = cd[i]; } }
    } else if (kind == 2) {
        const float* s0 = H2 + (size_t)r * NFULL;
        float* dst = ws + WS_Q2 + (size_t)r * NFULL;
#pragma unroll
        for (int u = 0; u < 16; ++u) { int i = t + u * 256; dst[i] = s0[i] / cd[i]; }
        if (r == 0) { float* d2 = ws + WS_D2;
#pragma unroll
            for (int u = 0; u < 16; ++u) { int i = t + u * 256; d2[i] = cd[i]; } }
    } else if (kind == 3) {
        const float* s0 = G2 + (size_t)r * NFULL;
        float* dst = ws + WS_GP2 + (size_t)r * NFULL;
#pragma unroll
        for (int u = 0; u < 16; ++u) { int i = t + u * 256; dst[i] = s0[i] / cd[i]; }
        if (r == 0) { float* c2 = ws + WS_C2;
#pragma unroll
            for (int u = 0; u < 16; ++u) { int i = t + u * 256; c2[i] = cd[i]; } }
    } else {
        unsigned short* p1h = (unsigned short*)(ws + WS_P1);
        unsigned short* p1l = p1h + BATCH * NIN;
        int row0 = r * 4;
#pragma unroll
        for (int u = 0; u < 16; ++u) {
            int lin = t + u * 256;                 // 0..4095
            int row = row0 + (lin >> 10), col = lin & 1023;
            float f = x[(size_t)row * NIN + col] * cd[col];
            unsigned short h = f2b(f);
            p1h[(size_t)row * NIN + col] = h;
            p1l[(size_t)row * NIN + col] = f2b(f - b2f(h));
        }
    }
}

// ---------------------------------------------------------------------------
// Rank-K outer-product GEMMs, both in one launch (z: 0 = M1, 1 = M2).
__global__ void __launch_bounds__(256) gemm_rank_kernel(float* __restrict__ ws) {
    const int which = blockIdx.z;
    if (which == 1 && blockIdx.y >= 8) return;
    const float* A = ws + (which == 0 ? WS_Q1  : WS_GP2);
    const float* B = ws + (which == 0 ? WS_GP1 : WS_Q2);
    float* C       = ws + (which == 0 ? WS_PT1 : WS_P2M);
    const int Kr   = which == 0 ? R1 : R2;
    __shared__ float As[R1 * 68];
    __shared__ float Bs[R1 * 68];
    int tid = threadIdx.x;
    int tx = tid & 15, ty = tid >> 4;
    int n0 = blockIdx.x * 64;
    int m0 = blockIdx.y * 64;
    int nf4 = Kr * 16;
    for (int lin = tid; lin < nf4; lin += 256) {
        int r = lin >> 4, i4 = lin & 15;
        *(float4*)&As[r * 68 + i4 * 4] = *(const float4*)&A[(size_t)r * NFULL + m0 + i4 * 4];
        *(float4*)&Bs[r * 68 + i4 * 4] = *(const float4*)&B[(size_t)r * NFULL + n0 + i4 * 4];
    }
    __syncthreads();
    float acc[4][4] = {};
#pragma unroll 8
    for (int r = 0; r < Kr; ++r) {
        float4 a4 = *(const float4*)&As[r * 68 + ty * 4];
        float4 b4 = *(const float4*)&Bs[r * 68 + tx * 4];
        acc[0][0] += a4.x * b4.x; acc[0][1] += a4.x * b4.y;
        acc[0][2] += a4.x * b4.z; acc[0][3] += a4.x * b4.w;
        acc[1][0] += a4.y * b4.x; acc[1][1] += a4.y * b4.y;
        acc[1][2] += a4.y * b4.z; acc[1][3] += a4.y * b4.w;
        acc[2][0] += a4.z * b4.x; acc[2][1] += a4.z * b4.y;
        acc[2][2] += a4.z * b4.z; acc[2][3] += a4.z * b4.w;
        acc[3][0] += a4.w * b4.x; acc[3][1] += a4.w * b4.y;
        acc[3][2] += a4.w * b4.z; acc[3][3] += a4.w * b4.w;
    }
#pragma unroll
    for (int i = 0; i < 4; ++i) {
        int m = m0 + ty * 4 + i;
        *(float4*)&C[(size_t)m * NFULL + n0 + tx * 4] =
            make_float4(acc[i][0], acc[i][1], acc[i][2], acc[i][3]);
    }
}

// ---------------------------------------------------------------------------
// Chunked diagonal prefix sum, phase 1. 64-row chunks for both matrices.
__global__ void diag_scan_p1(float* __restrict__ ws) {
    const int which = blockIdx.z;
    const int nch   = which == 0 ? NCH1 : NCH2;
    if (blockIdx.y >= (unsigned)nch) return;
    float* P        = ws + (which == 0 ? WS_PT1 : WS_P2M);
    float* ctot     = ws + (which == 0 ? WS_CT1 : WS_CT2);
    const int R     = which == 0 ? NIN : FCDIM;
    const int nd    = R + NFULL - 1;
    const int ctld  = which == 0 ? CTLD1 : CTLD2;
    int t = blockIdx.x * 256 + threadIdx.x;
    if (t >= nd) return;
    int doff = t - (R - 1);
    int z = blockIdx.y;
    int m0 = z * CHROWS;
    int mlo = max(m0, -doff);
    int mhi = min(m0 + CHROWS, min(NFULL - doff, R));
    float run = 0.f;
    if (mlo < mhi) {
        float* p = P + (size_t)mlo * NFULL + (mlo + doff);
        const size_t step = NFULL + 1;
        int len = mhi - mlo;
        int s = 0;
        for (; s + 16 <= len; s += 16) {
            float v[16];
#pragma unroll
            for (int u = 0; u < 16; ++u) v[u] = p[u * step];
#pragma unroll
            for (int u = 0; u < 16; ++u) { run += v[u]; v[u] = run; }
#pragma unroll
            for (int u = 0; u < 16; ++u) p[u * step] = v[u];
            p += 16 * step;
        }
        for (; s < len; ++s) { float v = *p; run += v; *p = run; p += step; }
    }
    ctot[(size_t)z * ctld + t] = run;
}

// In-place exclusive prefix over z of the chunk totals: ctot -> OFF.
__global__ void off_prefix(float* __restrict__ ws) {
    const int which = blockIdx.z;
    float* ct      = ws + (which == 0 ? WS_CT1 : WS_CT2);
    const int ctld = which == 0 ? CTLD1 : CTLD2;
    const int nch  = which == 0 ? NCH1 : NCH2;
    int t = blockIdx.x * 256 + threadIdx.x;
    if (t >= ctld) return;
    float run = 0.f;
    for (int z = 0; z < nch; ++z) {
        float v = ct[(size_t)z * ctld + t];
        ct[(size_t)z * ctld + t] = run;
        run += v;
    }
}

// ---------------------------------------------------------------------------
// Layer-1 GEMM2 via split-precision bf16 MFMA (D = Ah*Bh + Ah*Bl + Al*Bh).
// Grid (64,1,4), 512 thr = 8 waves (4 m-quads x 2 n-halves); tile 128m x 64n,
// K-chunk 256 (8 K32-steps). B staged per step: fp32 P1 + OFF -> hi/lo bf16
// packed u32 (k-pairs) in LDS. A frags are direct 16B loads from p1 planes.
// Fragment k-mapping (A and B identical): k = kbase + ks*32 + 8*(lane>>4) + reg.
// C/D mapping (m89-verified): col = lane&15, row = (lane>>4)*4 + reg.
#define L1_LOADA(H0, H1, L0, L1v, KS) { \
    int kk_ = kbase + (KS) * 32 + 8 * g; \
    const unsigned short* pa_ = p1h + (size_t)(mq * 32 + lm) * NIN + kk_; \
    const unsigned short* pb_ = p1l + (size_t)(mq * 32 + lm) * NIN + kk_; \
    H0 = *(const bf16x8*)pa_;  H1 = *(const bf16x8*)(pa_ + 16 * NIN); \
    L0 = *(const bf16x8*)pb_;  L1v = *(const bf16x8*)(pb_ + 16 * NIN); }

#define L1_LOADS(KS) { \
    int kg_ = kbase + (KS) * 32 + 2 * k2; \
    const float* pr_ = P1 + (size_t)kg_ * NFULL + n0 + 2 * n2; \
    float2 va_ = *(const float2*)pr_; \
    float2 vb_ = *(const float2*)(pr_ + NFULL); \
    const float* orow_ = OFF1 + (size_t)(kg_ >> 6) * CTLD1 + (1023 + n0 + 2 * n2 - kg_); \
    float om_ = orow_[-1], oc_ = orow_[0], op_ = orow_[1]; \
    f00 = va_.x + oc_; f01 = va_.y + op_; f10 = vb_.x + om_; f11 = vb_.y + oc_; }

#define L1_WRITES() { \
    unsigned short h00_ = f2b(f00), h10_ = f2b(f10), h01_ = f2b(f01), h11_ = f2b(f11); \
    int a0_ = (2 * n2) * 20 + k2; \
    Bh[a0_]      = (unsigned)h00_ | ((unsigned)h10_ << 16); \
    Bh[a0_ + 20] = (unsigned)h01_ | ((unsigned)h11_ << 16); \
    Bl[a0_]      = (unsigned)f2b(f00 - b2f(h00_)) | ((unsigned)f2b(f10 - b2f(h10_)) << 16); \
    Bl[a0_ + 20] = (unsigned)f2b(f01 - b2f(h01_)) | ((unsigned)f2b(f11 - b2f(h11_)) << 16); }

#define L1_COMPUTE(H0, H1, L0, L1v) { \
    int nb_ = (nh * 32 + lm) * 20 + 4 * g; \
    uint4 uh0_ = *(const uint4*)&Bh[nb_];       uint4 ul0_ = *(const uint4*)&Bl[nb_]; \
    uint4 uh1_ = *(const uint4*)&Bh[nb_ + 320]; uint4 ul1_ = *(const uint4*)&Bl[nb_ + 320]; \
    bf16x8 bh0_ = __builtin_bit_cast(bf16x8, uh0_), bl0_ = __builtin_bit_cast(bf16x8, ul0_); \
    bf16x8 bh1_ = __builtin_bit_cast(bf16x8, uh1_), bl1_ = __builtin_bit_cast(bf16x8, ul1_); \
    acc00 = MFMA16(H0, bh0_, acc00); acc10 = MFMA16(H1, bh0_, acc10); \
    acc01 = MFMA16(H0, bh1_, acc01); acc11 = MFMA16(H1, bh1_, acc11); \
    acc00 = MFMA16(H0, bl0_, acc00); acc10 = MFMA16(H1, bl0_, acc10); \
    acc01 = MFMA16(H0, bl1_, acc01); acc11 = MFMA16(H1, bl1_, acc11); \
    acc00 = MFMA16(L0, bh0_, acc00); acc10 = MFMA16(L1v, bh0_, acc10); \
    acc01 = MFMA16(L0, bh1_, acc01); acc11 = MFMA16(L1v, bh1_, acc11); }

#define L1_STEP(CH0, CH1, CL0, CL1, NH0, NH1, NL0, NL1, KS, LAST) \
    __syncthreads(); \
    L1_WRITES(); \
    if (!(LAST)) { L1_LOADS((KS) + 1); L1_LOADA(NH0, NH1, NL0, NL1, (KS) + 1); } \
    __syncthreads(); \
    L1_COMPUTE(CH0, CH1, CL0, CL1);

__global__ void __launch_bounds__(512)
gemm2_l1_mfma(const float* __restrict__ P1, const float* __restrict__ OFF1,
              const unsigned short* __restrict__ p1h,
              const unsigned short* __restrict__ p1l, float* __restrict__ vp) {
    __shared__ unsigned Bh[64 * 20];
    __shared__ unsigned Bl[64 * 20];
    const int t = threadIdx.x;
    const int n0 = blockIdx.x * 64;
    const int kbase = blockIdx.z * 256;
    const int w = t >> 6, l = t & 63;
    const int mq = w >> 1, nh = w & 1;
    const int lm = l & 15, g = l >> 4;
    const int k2 = t >> 5, n2 = t & 31;

    f32x4 zero = {0.f, 0.f, 0.f, 0.f};
    f32x4 acc00 = zero, acc01 = zero, acc10 = zero, acc11 = zero;
    bf16x8 ahA0, ahA1, alA0, alA1, ahB0, ahB1, alB0, alB1;
    float f00, f01, f10, f11;

    L1_LOADS(0);
    L1_LOADA(ahA0, ahA1, alA0, alA1, 0);
    L1_STEP(ahA0, ahA1, alA0, alA1, ahB0, ahB1, alB0, alB1, 0, 0)
    L1_STEP(ahB0, ahB1, alB0, alB1, ahA0, ahA1, alA0, alA1, 1, 0)
    L1_STEP(ahA0, ahA1, alA0, alA1, ahB0, ahB1, alB0, alB1, 2, 0)
    L1_STEP(ahB0, ahB1, alB0, alB1, ahA0, ahA1, alA0, alA1, 3, 0)
    L1_STEP(ahA0, ahA1, alA0, alA1, ahB0, ahB1, alB0, alB1, 4, 0)
    L1_STEP(ahB0, ahB1, alB0, alB1, ahA0, ahA1, alA0, alA1, 5, 0)
    L1_STEP(ahA0, ahA1, alA0, alA1, ahB0, ahB1, alB0, alB1, 6, 0)
    L1_STEP(ahB0, ahB1, alB0, alB1, ahA0, ahA1, alA0, alA1, 7, 1)

    float* dst = vp + (size_t)blockIdx.z * BATCH * NFULL;
    int row0 = mq * 32 + 4 * g;
    int col0 = n0 + nh * 32 + lm;
#pragma unroll
    for (int r = 0; r < 4; ++r) {
        dst[(size_t)(row0 + r) * NFULL + col0]           = acc00[r];
        dst[(size_t)(row0 + r) * NFULL + col0 + 16]      = acc01[r];
        dst[(size_t)(row0 + 16 + r) * NFULL + col0]      = acc10[r];
        dst[(size_t)(row0 + 16 + r) * NFULL + col0 + 16] = acc11[r];
    }
}

// reduce + epilogue: p2 = relu(c1*(sum of 4 partials) + b1) * d2, emitted as
// hi/lo bf16 planes for the MFMA layer-2 GEMM.
__global__ void reduce_l1_kernel(const float* __restrict__ vp, const float* __restrict__ c1,
                                 const float* __restrict__ b1, const float* __restrict__ d2,
                                 unsigned short* __restrict__ p2h,
                                 unsigned short* __restrict__ p2l) {
    int idx4 = blockIdx.x * 256 + threadIdx.x;     // 131072 float4s
    int base = idx4 * 4;
    int n = base & (NFULL - 1);
    float4 s = make_float4(0.f, 0.f, 0.f, 0.f);
#pragma unroll
    for (int z = 0; z < 4; ++z) {
        float4 v = *(const float4*)&vp[(size_t)z * BATCH * NFULL + base];
        s.x += v.x; s.y += v.y; s.z += v.z; s.w += v.w;
    }
    float4 cc = *(const float4*)&c1[n];
    float4 bb = *(const float4*)&b1[n];
    float4 dd = *(const float4*)&d2[n];
    float f[4];
    f[0] = fmaxf(cc.x * s.x + bb.x, 0.f) * dd.x;
    f[1] = fmaxf(cc.y * s.y + bb.y, 0.f) * dd.y;
    f[2] = fmaxf(cc.z * s.z + bb.z, 0.f) * dd.z;
    f[3] = fmaxf(cc.w * s.w + bb.w, 0.f) * dd.w;
    ushort4 hv, lv;
    unsigned short h;
    h = f2b(f[0]); hv.x = h; lv.x = f2b(f[0] - b2f(h));
    h = f2b(f[1]); hv.y = h; lv.y = f2b(f[1] - b2f(h));
    h = f2b(f[2]); hv.z = h; lv.z = f2b(f[2] - b2f(h));
    h = f2b(f[3]); hv.w = h; lv.w = f2b(f[3] - b2f(h));
    *(ushort4*)&p2h[base] = hv;
    *(ushort4*)&p2l[base] = lv;
}

// ---------------------------------------------------------------------------
// Layer-2 GEMM2 via split-precision bf16 MFMA. No LDS: B frags built per lane
// from k-contiguous M2 rows (M2 stored [n][k]) + OFF2 fold. Grid (8,1,32),
// 512 thr = 8 waves; tile 128m x 64n; K-chunk 128 (4 K32-steps).
__global__ void __launch_bounds__(512)
gemm2_l2_mfma(const unsigned short* __restrict__ p2h,
              const unsigned short* __restrict__ p2l,
              const float* __restrict__ M2, const float* __restrict__ OFF2,
              float* __restrict__ vp) {
    const int t = threadIdx.x;
    const int n0 = blockIdx.x * 64;
    const int kbase = blockIdx.z * 128;
    const int w = t >> 6, l = t & 63;
    const int mq = w >> 1, nh = w & 1;
    const int lm = l & 15, g = l >> 4;
    f32x4 zero = {0.f, 0.f, 0.f, 0.f};
    f32x4 acc00 = zero, acc01 = zero, acc10 = zero, acc11 = zero;
    const int nn0 = n0 + nh * 32 + lm;           // ni=0 B-row; ni=1 is nn0+16
    const int nn1 = nn0 + 16;
    const float* om0 = OFF2 + (size_t)(nn0 >> 6) * CTLD2 + (511 - nn0);
    const float* om1 = OFF2 + (size_t)(nn1 >> 6) * CTLD2 + (511 - nn1);
#pragma unroll
    for (int ks = 0; ks < 4; ++ks) {
        int kk = kbase + ks * 32 + 8 * g;
        const unsigned short* pa = p2h + (size_t)(mq * 32 + lm) * NFULL + kk;
        const unsigned short* pb = p2l + (size_t)(mq * 32 + lm) * NFULL + kk;
        bf16x8 ah0 = *(const bf16x8*)pa, ah1 = *(const bf16x8*)(pa + 16 * NFULL);
        bf16x8 al0 = *(const bf16x8*)pb, al1 = *(const bf16x8*)(pb + 16 * NFULL);
        bf16x8 bh0, bl0, bh1, bl1;
        {
            const float* pm = M2 + (size_t)nn0 * NFULL + kk;
#pragma unroll
            for (int r = 0; r < 8; ++r) {
                float f = pm[r] + om0[kk + r];
                unsigned short h = f2b(f);
                bh0[r] = (short)h; bl0[r] = (short)f2b(f - b2f(h));
            }
        }
        {
            const float* pm = M2 + (size_t)nn1 * NFULL + kk;
#pragma unroll
            for (int r = 0; r < 8; ++r) {
                float f = pm[r] + om1[kk + r];
                unsigned short h = f2b(f);
                bh1[r] = (short)h; bl1[r] = (short)f2b(f - b2f(h));
            }
        }
        acc00 = MFMA16(ah0, bh0, acc00); acc10 = MFMA16(ah1, bh0, acc10);
        acc01 = MFMA16(ah0, bh1, acc01); acc11 = MFMA16(ah1, bh1, acc11);
        acc00 = MFMA16(ah0, bl0, acc00); acc10 = MFMA16(ah1, bl0, acc10);
        acc01 = MFMA16(ah0, bl1, acc01); acc11 = MFMA16(ah1, bl1, acc11);
        acc00 = MFMA16(al0, bh0, acc00); acc10 = MFMA16(al1, bh0, acc10);
        acc01 = MFMA16(al0, bh1, acc01); acc11 = MFMA16(al1, bh1, acc11);
    }
    float* dst = vp + (size_t)blockIdx.z * BATCH * FCDIM;
    int row0 = mq * 32 + 4 * g;
    int col0 = n0 + nh * 32 + lm;
#pragma unroll
    for (int r = 0; r < 4; ++r) {
        dst[(size_t)(row0 + r) * FCDIM + col0]           = acc00[r];
        dst[(size_t)(row0 + r) * FCDIM + col0 + 16]      = acc01[r];
        dst[(size_t)(row0 + 16 + r) * FCDIM + col0]      = acc10[r];
        dst[(size_t)(row0 + 16 + r) * FCDIM + col0 + 16] = acc11[r];
    }
}

// ---------------------------------------------------------------------------
// Fused L2 reduce + epilogue + logits. One block per batch row.
__global__ void fused_out_kernel(const float* __restrict__ vp, const float* __restrict__ c2,
                                 const float* __restrict__ b2, const float* __restrict__ Wl,
                                 const float* __restrict__ bl, float* __restrict__ out) {
    __shared__ float h2s[FCDIM];
    int b = blockIdx.x, t = threadIdx.x;
    for (int col = t; col < FCDIM; col += 256) {
        float s = 0.f;
#pragma unroll
        for (int z = 0; z < 32; ++z)
            s += vp[((size_t)z * BATCH + b) * FCDIM + col];
        h2s[col] = fmaxf(c2[col] * s + b2[col], 0.f);
    }
    __syncthreads();
    int w = t >> 6, lane = t & 63;
    for (int o = w; o < NOUT; o += 4) {
        float s = 0.f;
#pragma unroll
        for (int i = lane; i < FCDIM; i += 64) s += h2s[i] * Wl[(size_t)o * FCDIM + i];
#pragma unroll
        for (int off = 32; off > 0; off >>= 1) s += __shfl_down(s, off);
        if (lane == 0) out[(size_t)b * NOUT + o] = s + bl[o];
    }
}

// ---------------------------------------------------------------------------
extern "C" void kernel_launch(void* const* d_in, const int* in_sizes, int n_in,
                              void* d_out, int out_size, void* d_ws, size_t ws_size,
                              hipStream_t stream) {
    const float* x   = (const float*)d_in[0];
    const float* G1  = (const float*)d_in[1];
    const float* H1  = (const float*)d_in[2];
    const float* sA1 = (const float*)d_in[3];
    const float* sB1 = (const float*)d_in[4];
    const float* b1  = (const float*)d_in[5];
    const float* G2  = (const float*)d_in[6];
    const float* H2  = (const float*)d_in[7];
    const float* sA2 = (const float*)d_in[8];
    const float* sB2 = (const float*)d_in[9];
    const float* b2  = (const float*)d_in[10];
    const float* Wl  = (const float*)d_in[11];
    const float* bl  = (const float*)d_in[12];
    float* out = (float*)d_out;
    float* ws = (float*)d_ws;
    (void)in_sizes; (void)n_in; (void)out_size; (void)ws_size;

    unsigned short* p1h = (unsigned short*)(ws + WS_P1);
    unsigned short* p1l = p1h + BATCH * NIN;
    unsigned short* p2h = (unsigned short*)(ws + WS_P2);
    unsigned short* p2l = p2h + BATCH * NFULL;

    // 1. fused cumprod + prep: c/d vectors, q1, gp1, q2, gp2, p1 (hi/lo)
    prep_fused<<<160, 256, 0, stream>>>(x, G1, H1, G2, H2, sA1, sB1, sA2, sB2, ws);

    // 2. Both rank-K GEMMs in one launch (z=0: Pt1 1024x4096, z=1: P2M 512x4096)
    gemm_rank_kernel<<<dim3(64, 16, 2), 256, 0, stream>>>(ws);

    // 3. Chunk-local diagonal scans (64-row chunks) + chunk totals
    diag_scan_p1<<<dim3(20, NCH1, 2), 256, 0, stream>>>(ws);
    //    chunk totals -> exclusive offsets (in place)
    off_prefix<<<dim3(20, 1, 2), 256, 0, stream>>>(ws);

    // 4. GEMM2 layer 1 (split-precision bf16 MFMA) -> 4 partial slices
    gemm2_l1_mfma<<<dim3(64, 1, 4), 512, 0, stream>>>(ws + WS_PT1, ws + WS_CT1,
                                                      p1h, p1l, ws + WS_VP1);
    //    reduce + epilogue -> p2 (hi/lo planes)
    reduce_l1_kernel<<<512, 256, 0, stream>>>(ws + WS_VP1, ws + WS_C1, b1, ws + WS_D2,
                                              p2h, p2l);

    // 5. GEMM2 layer 2 (split-precision bf16 MFMA, split-K=32) -> partials
    gemm2_l2_mfma<<<dim3(8, 1, 32), 512, 0, stream>>>(p2h, p2l, ws + WS_P2M,
                                                      ws + WS_CT2, ws + WS_VP2);

    // 6. fused reduce + epilogue + logits
    fused_out_kernel<<<BATCH, 256, 0, stream>>>(ws + WS_VP2, ws + WS_C2, b2, Wl, bl, out);
}